// Round 10
// baseline (1102.215 us; speedup 1.0000x reference)
//
#include <hip/hip_runtime.h>
#include <hip/hip_bf16.h>

typedef unsigned short u16;
typedef __attribute__((ext_vector_type(4))) float f32x4;
typedef __attribute__((ext_vector_type(8))) short s16x8;

#define DEVI __device__ __forceinline__

static constexpr int NPATCH = 676;
static constexpr int KSEL   = 540;   // int(676*0.8)
static constexpr int NLOW   = 136;
static constexpr int BB     = 32;
static constexpr int CC     = 1024;
static constexpr int S      = 542;   // 1 + 540 + 1
static constexpr int SP     = 576;   // padded seq (9*64)
static constexpr int M1P    = SP * BB;     // 18432 rows, seq-major: m = b*SP + s
static constexpr int NTOK   = 677;
static constexpr int M2     = NTOK * BB;   // 21664
static constexpr int M2P    = 21760;       // pad to 128/256
static constexpr int NKT    = SP / 64;     // 9 kv tiles
static constexpr int NQC    = 5;           // q-chunks of 8 qtiles (36 qtiles total)

DEVI u16 f2bf(float f) {
  unsigned u = __float_as_uint(f);
  u += 0x7fffu + ((u >> 16) & 1u);
  return (u16)(u >> 16);
}
DEVI float bf2f(u16 h) { return __uint_as_float(((unsigned)h) << 16); }
DEVI float ex2(float x) { float r; asm("v_exp_f32 %0, %1" : "=v"(r) : "v"(x)); return r; }

DEVI void gld16(const void* g, void* l) {
  __builtin_amdgcn_global_load_lds((const __attribute__((address_space(1))) void*)g,
                                   (__attribute__((address_space(3))) void*)l,
                                   16, 0, 0);
}

DEVI void BAR() {
  asm volatile("" ::: "memory");
  __builtin_amdgcn_s_barrier();
  asm volatile("" ::: "memory");
}
#define VMC(N) asm volatile("s_waitcnt vmcnt(" #N ")" ::: "memory")

// ---------------- small kernels ----------------

__global__ void k_f2bf4(const float* __restrict__ in, u16* __restrict__ out, int n4) {
  int i = blockIdx.x * blockDim.x + threadIdx.x;
  if (i >= n4) return;
  float4 v = ((const float4*)in)[i];
  unsigned long long p = (unsigned long long)f2bf(v.x)
                       | ((unsigned long long)f2bf(v.y) << 16)
                       | ((unsigned long long)f2bf(v.z) << 32)
                       | ((unsigned long long)f2bf(v.w) << 48);
  *(unsigned long long*)&out[(long)i * 4] = p;
}

__global__ void k_langmean(const float* __restrict__ lang, float* __restrict__ lm) {
  int b = blockIdx.x, t = threadIdx.x;
  float a0 = 0, a1 = 0, a2 = 0, a3 = 0;
  for (int l = 0; l < 77; l++) {
    float4 v = ((const float4*)(lang + ((long)l * BB + b) * CC))[t];
    a0 += v.x; a1 += v.y; a2 += v.z; a3 += v.w;
  }
  const float inv = 1.f / 77.f;
  float4 o; o.x = a0 * inv; o.y = a1 * inv; o.z = a2 * inv; o.w = a3 * inv;
  ((float4*)(lm + b * CC))[t] = o;
}

__global__ void k_score(const float* __restrict__ x, const float* __restrict__ lm,
                        float* __restrict__ score) {
  int nb = blockIdx.x;
  int n = nb >> 5, b = nb & 31;
  int t = threadIdx.x;
  float4 xv = ((const float4*)(x + ((long)(n + 1) * BB + b) * CC))[t];
  float4 lv = ((const float4*)(lm + b * CC))[t];
  float s = xv.x * lv.x + xv.y * lv.y + xv.z * lv.z + xv.w * lv.w;
  for (int m = 1; m < 64; m <<= 1) s += __shfl_xor(s, m);
  __shared__ float sm[4];
  if ((t & 63) == 0) sm[t >> 6] = s;
  __syncthreads();
  if (t == 0) score[n * BB + b] = sm[0] + sm[1] + sm[2] + sm[3];
}

__global__ void k_select(const float* __restrict__ score, float* __restrict__ wall,
                         int* __restrict__ rowmap, int* __restrict__ selsrc,
                         int* __restrict__ lowlist) {
  int b = blockIdx.x, t = threadIdx.x;
  __shared__ float sc[NPATCH];
  __shared__ int hf[NPATCH];
  __shared__ float red[2];
  if (t < NPATCH) sc[t] = score[t * BB + b];
  __syncthreads();
  int high = 0;
  if (t < NPATCH) {
    float s = sc[t];
    int r = 0;
    for (int m = 0; m < NPATCH; m++) {
      float sm_ = sc[m];
      r += (sm_ > s) || (sm_ == s && m < t);
    }
    high = (r < KSEL);
    hf[t] = high;
  }
  __syncthreads();
  if (t < NPATCH) {
    int p = 0;
    for (int m = 0; m < t; m++) p += hf[m];
    if (high) {
      rowmap[b * NPATCH + t] = 1 + p;
      selsrc[b * S + 1 + p] = t + 1;        // row index into full x
    } else {
      rowmap[b * NPATCH + t] = S - 1;
      lowlist[b * NLOW + (t - p)] = t;
    }
  }
  if (t == 0) selsrc[b * S + 0] = 0;
  __syncthreads();
  if (t == 0) {
    float m = -3e38f;
    for (int i = 0; i < NPATCH; i++) if (!hf[i]) m = fmaxf(m, sc[i]);
    float d = 0;
    for (int i = 0; i < NPATCH; i++) if (!hf[i]) d += __expf(sc[i] - m);
    red[0] = m; red[1] = d;
  }
  __syncthreads();
  if (t < NPATCH) wall[b * NPATCH + t] = hf[t] ? 0.f : __expf(sc[t] - red[0]) / red[1];
}

__global__ void k_lowtok(const float* __restrict__ x, const float* __restrict__ wall,
                         const int* __restrict__ lowlist, float* __restrict__ lowtok) {
  int b = blockIdx.x, ch = blockIdx.y;
  int c = ch * 256 + threadIdx.x;
  float acc = 0.f;
  for (int i = 0; i < NLOW; i++) {
    int n = lowlist[b * NLOW + i];
    acc += wall[b * NPATCH + n] * x[((long)(n + 1) * BB + b) * CC + c];
  }
  lowtok[b * CC + c] = acc;
}

// gather + LayerNorm -> bf16 seq rows, SEQ-MAJOR: row = b*SP + s (pad rows zeroed)
__global__ void k_lnseq(const float* __restrict__ x, const float* __restrict__ lowtok,
                        const int* __restrict__ selsrc, const float* __restrict__ w,
                        const float* __restrict__ bias, u16* __restrict__ out) {
  int s = blockIdx.x, b = blockIdx.y, t = threadIdx.x;
  u16* orow = out + ((long)b * SP + s) * CC;
  if (s >= S) { *(unsigned long long*)&orow[4 * t] = 0ULL; return; }
  const float* src;
  if (s == 0)          src = x + (long)b * CC;
  else if (s == S - 1) src = lowtok + (long)b * CC;
  else                 src = x + ((long)selsrc[b * S + s] * BB + b) * CC;
  float4 v = ((const float4*)src)[t];
  float ss = v.x + v.y + v.z + v.w;
  float s2 = v.x * v.x + v.y * v.y + v.z * v.z + v.w * v.w;
  for (int k = 1; k < 64; k <<= 1) { ss += __shfl_xor(ss, k); s2 += __shfl_xor(s2, k); }
  __shared__ float sa[4], sb[4];
  if ((t & 63) == 0) { sa[t >> 6] = ss; sb[t >> 6] = s2; }
  __syncthreads();
  ss = sa[0] + sa[1] + sa[2] + sa[3];
  s2 = sb[0] + sb[1] + sb[2] + sb[3];
  float mu = ss * (1.f / CC);
  float var = s2 * (1.f / CC) - mu * mu;
  float rs = rsqrtf(var + 1e-5f);
  int c = 4 * t;
  unsigned long long p = (unsigned long long)f2bf((v.x - mu) * rs * w[c]     + bias[c])
                       | ((unsigned long long)f2bf((v.y - mu) * rs * w[c + 1] + bias[c + 1]) << 16)
                       | ((unsigned long long)f2bf((v.z - mu) * rs * w[c + 2] + bias[c + 2]) << 32)
                       | ((unsigned long long)f2bf((v.w - mu) * rs * w[c + 3] + bias[c + 3]) << 48);
  *(unsigned long long*)&orow[4 * t] = p;
}

// fused scatter (x + gathered d -> out fp32) + LayerNorm(out) -> bf16
__global__ void k_scatln(const float* __restrict__ x, const u16* __restrict__ dbuf,
                         const int* __restrict__ rowmap, const float* __restrict__ w,
                         const float* __restrict__ bias, float* __restrict__ out,
                         u16* __restrict__ lnout) {
  int m = blockIdx.x, t = threadIdx.x;
  u16* orow = lnout + (long)m * CC;
  if (m >= M2) { *(unsigned long long*)&orow[4 * t] = 0ULL; return; }
  int nf = m >> 5, b = m & 31;
  int srow = (nf == 0) ? 0 : rowmap[b * NPATCH + (nf - 1)];
  float4 xv = ((const float4*)(x + (long)m * CC))[t];
  unsigned long long dp = *(const unsigned long long*)&dbuf[((long)b * SP + srow) * CC + 4 * t];
  float4 v;
  v.x = xv.x + bf2f((u16)(dp));
  v.y = xv.y + bf2f((u16)(dp >> 16));
  v.z = xv.z + bf2f((u16)(dp >> 32));
  v.w = xv.w + bf2f((u16)(dp >> 48));
  ((float4*)(out + (long)m * CC))[t] = v;
  float ss = v.x + v.y + v.z + v.w;
  float s2 = v.x * v.x + v.y * v.y + v.z * v.z + v.w * v.w;
  for (int k = 1; k < 64; k <<= 1) { ss += __shfl_xor(ss, k); s2 += __shfl_xor(s2, k); }
  __shared__ float sa[4], sb[4];
  if ((t & 63) == 0) { sa[t >> 6] = ss; sb[t >> 6] = s2; }
  __syncthreads();
  ss = sa[0] + sa[1] + sa[2] + sa[3];
  s2 = sb[0] + sb[1] + sb[2] + sb[3];
  float mu = ss * (1.f / CC);
  float var = s2 * (1.f / CC) - mu * mu;
  float rs = rsqrtf(var + 1e-5f);
  int c = 4 * t;
  unsigned long long p = (unsigned long long)f2bf((v.x - mu) * rs * w[c]     + bias[c])
                       | ((unsigned long long)f2bf((v.y - mu) * rs * w[c + 1] + bias[c + 1]) << 16)
                       | ((unsigned long long)f2bf((v.z - mu) * rs * w[c + 2] + bias[c + 2]) << 32)
                       | ((unsigned long long)f2bf((v.w - mu) * rs * w[c + 3] + bias[c + 3]) << 48);
  *(unsigned long long*)&orow[4 * t] = p;
}

// ---------------- GEMM common ----------------

struct Epi {
  const float* bias;
  u16* obf;
  float* of;
  u16 *qb, *kb, *vtb;
  int mvalid, ldc;
};

// 128x32 K-step tile packed as 64 LDS-rows x 64 cols (8 KiB).
// LDS row R holds global rows {2R, 2R+1}; logical chunk lc (0..7):
//   m = 2R + (lc>>2), k-chunk = lc&3 (8 elems each).
// Physical chunk = lc ^ (R&7) (involution; pre-swizzled global source,
// linear LDS dest for global_load_lds, swizzled read).
DEVI void stage32(u16* dst, const u16* src, int ld) {
  int t = threadIdx.x;
#pragma unroll
  for (int q = 0; q < 2; q++) {
    int s = t + q * 256;
    int R = s >> 3, clp = s & 7;
    int lc = clp ^ (R & 7);
    int m = 2 * R + (lc >> 2), kc = lc & 3;
    gld16(src + (long)m * ld + kc * 8, dst + s * 8);
  }
}

DEVI s16x8 frag32(const u16* tile, int m, int h4) {
  int R = m >> 1;
  int phys = ((((m & 1) << 2) | h4) ^ (R & 7));
  return *(const s16x8*)(tile + R * 64 + phys * 8);
}

// attn helpers (64-row x 64-col tiles, verified swizzle pair)
DEVI void stage64(u16* dst, const u16* src, int ld) {
  int t = threadIdx.x;
  int c = t & 7, r0 = t >> 3;             // rows 0..31
  gld16(src + (long)r0 * ld + ((c ^ (r0 & 7)) << 3), dst + t * 8);
  int r1 = r0 + 32;
  gld16(src + (long)r1 * ld + ((c ^ (r1 & 7)) << 3), dst + 2048 + t * 8);
}

DEVI s16x8 frag(const u16* half, int rh, int kk, int h4) {
  int chunk = ((kk << 2) | h4) ^ (rh & 7);
  return *(const s16x8*)(half + rh * 64 + chunk * 8);
}

// shared epilogue element-writer
template<int MODE>
DEVI void epi_store(const Epi& e, int m0, int n, const f32x4& a, float bias) {
  const float QSC = 0.125f * 1.44269504088896f;
  if (MODE == 0) {
    int part = n >> 10, cc = n & 1023;
    int hh = cc >> 6, dd = cc & 63;
    int b0 = m0 / SP, s0 = m0 % SP;
    if (part == 2) {
      u16 pk[4];
#pragma unroll
      for (int tt = 0; tt < 4; tt++) pk[tt] = f2bf(a[tt] + bias);
      *(unsigned long long*)&e.vtb[((long)(b0 * 16 + hh) * 64 + dd) * SP + s0] =
          *(unsigned long long*)pk;
    } else {
      u16* dst = (part == 0 ? e.qb : e.kb) + ((long)(b0 * 16 + hh) * SP + s0) * 64 + dd;
      float scl = (part == 0) ? QSC : 1.f;
#pragma unroll
      for (int tt = 0; tt < 4; tt++) dst[tt * 64] = f2bf((a[tt] + bias) * scl);
    }
  } else if (MODE == 1) {
#pragma unroll
    for (int tt = 0; tt < 4; tt++)
      e.obf[(long)(m0 + tt) * e.ldc + n] = f2bf(a[tt] + bias);
  } else if (MODE == 2) {
#pragma unroll
    for (int tt = 0; tt < 4; tt++) {
      float v = a[tt] + bias;
      v = v / (1.f + __expf(-1.702f * v));
      e.obf[(long)(m0 + tt) * e.ldc + n] = f2bf(v);
    }
  } else {
#pragma unroll
    for (int tt = 0; tt < 4; tt++) {
      int m = m0 + tt;
      if (m < e.mvalid) e.of[(long)m * CC + n] += a[tt] + bias;
    }
  }
}

// -- GEMM v5: 128x128 tile, BK=32, 3-buffer rotation, counted vmcnt (outproj/fc2) --

template<int MODE>
__global__ __launch_bounds__(256, 3) void k_gemm5(const u16* __restrict__ A, int lda,
                                                  const u16* __restrict__ Bw, int ldb,
                                                  int K, Epi e) {
  __shared__ __align__(16) u16 lds[3][2][4096];  // 48 KiB -> 3 blk/CU
  int t = threadIdx.x;
  int lane = t & 63, w = t >> 6;
  int h4 = lane >> 4, r = lane & 15;
  int wr = w >> 1, wc = w & 1;
  int MBk = gridDim.x, NBk = gridDim.y;
  int nwg = MBk * NBk;
  int orig = blockIdx.y * MBk + blockIdx.x;
  int q8 = nwg >> 3, r8 = nwg & 7, xcd = orig & 7, rk = orig >> 3;
  int wgid = (xcd < r8 ? xcd * (q8 + 1) : r8 * (q8 + 1) + (xcd - r8) * q8) + rk;
  int bm = wgid / NBk, bn = wgid % NBk;

  const u16* Asrc = A + (long)bm * 128 * lda;
  const u16* Bsrc = Bw + (long)bn * 128 * ldb;
  int NT = K >> 5;

  f32x4 acc[4][4];
#pragma unroll
  for (int i = 0; i < 4; i++)
#pragma unroll
    for (int j = 0; j < 4; j++) acc[i][j] = {0.f, 0.f, 0.f, 0.f};

  stage32(lds[0][0], Asrc, lda);
  stage32(lds[0][1], Bsrc, ldb);
  if (NT > 1) {
    stage32(lds[1][0], Asrc + 32, lda);
    stage32(lds[1][1], Bsrc + 32, ldb);
  }

  int bufr = 0, bufw = 2;
  for (int kt = 0; kt < NT; kt++) {
    if (kt + 1 < NT) { VMC(4); } else { VMC(0); }
    BAR();
    if (kt + 2 < NT) {
      stage32(lds[bufw][0], Asrc + (kt + 2) * 32, lda);
      stage32(lds[bufw][1], Bsrc + (kt + 2) * 32, ldb);
    }
    const u16* At = lds[bufr][0];
    const u16* Bt = lds[bufr][1];
    s16x8 af[4], bf[4];
#pragma unroll
    for (int i = 0; i < 4; i++) af[i] = frag32(At, wr * 64 + i * 16 + r, h4);
#pragma unroll
    for (int j = 0; j < 4; j++) bf[j] = frag32(Bt, wc * 64 + j * 16 + r, h4);
#pragma unroll
    for (int i = 0; i < 4; i++)
#pragma unroll
      for (int j = 0; j < 4; j++)
        acc[i][j] = __builtin_amdgcn_mfma_f32_16x16x32_bf16(af[i], bf[j], acc[i][j], 0, 0, 0);
    bufr = (bufr == 2) ? 0 : bufr + 1;
    bufw = (bufw == 2) ? 0 : bufw + 1;
  }

#pragma unroll
  for (int i = 0; i < 4; i++) {
    int m0 = bm * 128 + wr * 64 + i * 16 + 4 * h4;
#pragma unroll
    for (int j = 0; j < 4; j++) {
      int n = bn * 128 + wc * 64 + j * 16 + r;
      float bias = (MODE == 3 && e.bias == nullptr) ? 0.f : e.bias[n];
      epi_store<MODE>(e, m0, n, acc[i][j], bias);
    }
  }
}

// -- GEMM v6: 128x256 tile, BK=32, 2-buffer sync pipeline (QKV/fc1) --
// L2 traffic per FLOP x0.75 vs 128x128; 2 blocks/CU (VGPR-capped), 8 waves.

template<int MODE>
__global__ __launch_bounds__(256, 2) void k_gemm6(const u16* __restrict__ A, int lda,
                                                  const u16* __restrict__ Bw, int ldb,
                                                  int K, Epi e) {
  __shared__ __align__(16) u16 lds[2][3][4096];  // [buf][A,B-lo,B-hi] = 48 KiB
  int t = threadIdx.x;
  int lane = t & 63, w = t >> 6;
  int h4 = lane >> 4, r = lane & 15;
  int wr = w >> 1, wc = w & 1;          // per-wave 64 rows x 128 cols
  int MBk = gridDim.x, NBk = gridDim.y;
  int nwg = MBk * NBk;
  int orig = blockIdx.y * MBk + blockIdx.x;
  int q8 = nwg >> 3, r8 = nwg & 7, xcd = orig & 7, rk = orig >> 3;
  int wgid = (xcd < r8 ? xcd * (q8 + 1) : r8 * (q8 + 1) + (xcd - r8) * q8) + rk;
  int bm = wgid / NBk, bn = wgid % NBk;

  const u16* Asrc = A + (long)bm * 128 * lda;
  const u16* Bsrc = Bw + (long)bn * 256 * ldb;
  int NT = K >> 5;

  f32x4 acc[4][8];
#pragma unroll
  for (int i = 0; i < 4; i++)
#pragma unroll
    for (int j = 0; j < 8; j++) acc[i][j] = {0.f, 0.f, 0.f, 0.f};

  stage32(lds[0][0], Asrc, lda);
  stage32(lds[0][1], Bsrc, ldb);
  stage32(lds[0][2], Bsrc + (long)128 * ldb, ldb);
  __syncthreads();

  for (int kt = 0; kt < NT; kt++) {
    int cur = kt & 1;
    if (kt + 1 < NT) {
      stage32(lds[cur ^ 1][0], Asrc + (kt + 1) * 32, lda);
      stage32(lds[cur ^ 1][1], Bsrc + (kt + 1) * 32, ldb);
      stage32(lds[cur ^ 1][2], Bsrc + (long)128 * ldb + (kt + 1) * 32, ldb);
    }
    const u16* At = lds[cur][0];
    const u16* Bt = lds[cur][1 + wc];   // wc=0 -> n 0..127, wc=1 -> n 128..255
    s16x8 af[4], bf[8];
#pragma unroll
    for (int i = 0; i < 4; i++) af[i] = frag32(At, wr * 64 + i * 16 + r, h4);
#pragma unroll
    for (int j = 0; j < 8; j++) bf[j] = frag32(Bt, j * 16 + r, h4);
#pragma unroll
    for (int i = 0; i < 4; i++)
#pragma unroll
      for (int j = 0; j < 8; j++)
        acc[i][j] = __builtin_amdgcn_mfma_f32_16x16x32_bf16(af[i], bf[j], acc[i][j], 0, 0, 0);
    __syncthreads();   // drains vmcnt (next-tile stages) + syncs LDS reuse
  }

#pragma unroll
  for (int i = 0; i < 4; i++) {
    int m0 = bm * 128 + wr * 64 + i * 16 + 4 * h4;
#pragma unroll
    for (int j = 0; j < 8; j++) {
      int n = bn * 256 + wc * 128 + j * 16 + r;
      float bias = (MODE == 3 && e.bias == nullptr) ? 0.f : e.bias[n];
      epi_store<MODE>(e, m0, n, acc[i][j], bias);
    }
  }
}

// ---------------- flash attention v2: LDS-staged KV, 2-phase pipeline ----------------

__global__ __launch_bounds__(256, 4) void k_attn2(const u16* __restrict__ qb,
                                                  const u16* __restrict__ kb,
                                                  const u16* __restrict__ vtb,
                                                  u16* __restrict__ aout) {
  __shared__ __align__(16) u16 Kt[2][4096];
  __shared__ __align__(16) u16 Vt[2][4096];
  __shared__ __align__(16) u16 Pl[4][1024];

  int nwg = gridDim.x;                   // 2560
  int orig = blockIdx.x;
  int q8 = nwg >> 3, r8 = nwg & 7, xcd = orig & 7, rk = orig >> 3;
  int wgid = (xcd < r8 ? xcd * (q8 + 1) : r8 * (q8 + 1) + (xcd - r8) * q8) + rk;
  int bh = wgid / NQC, qc = wgid % NQC;  // all q-chunks of a (b,h) contiguous -> same XCD
  int b = bh >> 4, hh = bh & 15;
  int t = threadIdx.x, w = t >> 6, lane = t & 63;
  int h4 = lane >> 4, r = lane & 15;

  const u16* Q  = qb  + (long)bh * SP * 64;
  const u16* Kg = kb  + (long)bh * SP * 64;
  const u16* Vg = vtb + (long)bh * 64 * SP;

  int qt[2];
  bool act[2];
  s16x8 aq0[2], aq1[2];
  f32x4 o[2][4];
  float mM[2][4], lL[2][4];
#pragma unroll
  for (int sub = 0; sub < 2; sub++) {
    qt[sub] = qc * 8 + w * 2 + sub;
    act[sub] = qt[sub] < SP / 16;
    if (act[sub]) {
      aq0[sub] = *(const s16x8*)&Q[(qt[sub] * 16 + r) * 64 + h4 * 8];
      aq1[sub] = *(const s16x8*)&Q[(qt[sub] * 16 + r) * 64 + 32 + h4 * 8];
    }
#pragma unroll
    for (int i = 0; i < 4; i++) { o[sub][i] = {0.f, 0.f, 0.f, 0.f}; mM[sub][i] = -1e30f; lL[sub][i] = 0.f; }
  }

  // prologue: stage tile 0
  stage64(Kt[0], Kg, 64);
  stage64(Vt[0], Vg, SP);
  VMC(0);
  BAR();

  for (int kt = 0; kt < NKT; kt++) {
    int cur = kt & 1;
    if (kt + 1 < NKT) {                 // issue next-tile loads (other buffer)
      stage64(Kt[cur ^ 1], Kg + (kt + 1) * 64 * 64, 64);
      stage64(Vt[cur ^ 1], Vg + (kt + 1) * 64, SP);
    }
    int kv0 = kt * 64;
    const u16* Kc = Kt[cur];
    const u16* Vc = Vt[cur];
#pragma unroll
    for (int sub = 0; sub < 2; sub++) {
      if (!act[sub]) continue;
      // ---- QK^T: S[q16][kv64]
      f32x4 sf[4];
#pragma unroll
      for (int f = 0; f < 4; f++) {
        sf[f] = {0.f, 0.f, 0.f, 0.f};
        sf[f] = __builtin_amdgcn_mfma_f32_16x16x32_bf16(aq0[sub], frag(Kc, f * 16 + r, 0, h4), sf[f], 0, 0, 0);
        sf[f] = __builtin_amdgcn_mfma_f32_16x16x32_bf16(aq1[sub], frag(Kc, f * 16 + r, 1, h4), sf[f], 0, 0, 0);
      }
      if (kv0 + 64 > S) {               // mask invalid kv columns
#pragma unroll
        for (int f = 0; f < 4; f++)
          if (kv0 + f * 16 + r >= S) {
#pragma unroll
            for (int tt = 0; tt < 4; tt++) sf[f][tt] = -1e30f;
          }
      }
      // ---- online softmax (base-2; Q pre-scaled by 0.125*log2e)
      float mx[4];
#pragma unroll
      for (int tt = 0; tt < 4; tt++)
        mx[tt] = fmaxf(fmaxf(sf[0][tt], sf[1][tt]), fmaxf(sf[2][tt], sf[3][tt]));
      for (int msk = 1; msk < 16; msk <<= 1) {
#pragma unroll
        for (int tt = 0; tt < 4; tt++) mx[tt] = fmaxf(mx[tt], __shfl_xor(mx[tt], msk));
      }
      int need = 0;
#pragma unroll
      for (int tt = 0; tt < 4; tt++) need |= (mx[tt] > mM[sub][tt] + 8.f);
      if (__any(need)) {                // rescale path (rare after first tile)
#pragma unroll
        for (int tt = 0; tt < 4; tt++) {
          float mn = fmaxf(mM[sub][tt], mx[tt]);
          float sc = ex2(mM[sub][tt] - mn);
          mM[sub][tt] = mn;
          lL[sub][tt] *= sc;
#pragma unroll
          for (int nf = 0; nf < 4; nf++) o[sub][nf][tt] *= sc;
        }
      }
      float rs[4];
#pragma unroll
      for (int tt = 0; tt < 4; tt++) {
        float m_ = mM[sub][tt];
        float p0 = ex2(sf[0][tt] - m_), p1 = ex2(sf[1][tt] - m_);
        float p2 = ex2(sf[2][tt] - m_), p3 = ex2(sf[3][tt] - m_);
        sf[0][tt] = p0; sf[1][tt] = p1; sf[2][tt] = p2; sf[3][tt] = p3;
        rs[tt] = (p0 + p1) + (p2 + p3);
      }
      for (int msk = 1; msk < 16; msk <<= 1) {
#pragma unroll
        for (int tt = 0; tt < 4; tt++) rs[tt] += __shfl_xor(rs[tt], msk);
      }
#pragma unroll
      for (int tt = 0; tt < 4; tt++) lL[sub][tt] += rs[tt];
      // ---- pack P -> LDS (round-to-nearest bf16), chunk-swizzled rows
      u16* Pw = Pl[w];
#pragma unroll
      for (int f = 0; f < 4; f++)
#pragma unroll
        for (int tt = 0; tt < 4; tt++) {
          int q = 4 * h4 + tt;
          int chunk = (f * 2 + (r >> 3)) ^ (q & 7);
          Pw[q * 64 + chunk * 8 + (r & 7)] = f2bf(sf[f][tt]);
        }
      // ---- PV
      s16x8 pa0 = frag(Pw, r, 0, h4);
      s16x8 pa1 = frag(Pw, r, 1, h4);
#pragma unroll
      for (int nf = 0; nf < 4; nf++) {
        o[sub][nf] = __builtin_amdgcn_mfma_f32_16x16x32_bf16(pa0, frag(Vc, nf * 16 + r, 0, h4), o[sub][nf], 0, 0, 0);
        o[sub][nf] = __builtin_amdgcn_mfma_f32_16x16x32_bf16(pa1, frag(Vc, nf * 16 + r, 1, h4), o[sub][nf], 0, 0, 0);
      }
    }
    VMC(0);
    BAR();
  }

  // ---- write output
#pragma unroll
  for (int sub = 0; sub < 2; sub++) {
    if (!act[sub]) continue;
    float inv[4];
#pragma unroll
    for (int tt = 0; tt < 4; tt++) inv[tt] = 1.f / lL[sub][tt];
#pragma unroll
    for (int nf = 0; nf < 4; nf++)
#pragma unroll
      for (int tt = 0; tt < 4; tt++) {
        int q = qt[sub] * 16 + 4 * h4 + tt;
        if (q < S) aout[((long)b * SP + q) * CC + hh * 64 + nf * 16 + r] = f2bf(o[sub][nf][tt] * inv[tt]);
      }
  }
}

// ---------------- launcher ----------------
// ws liveness map (MiB):
//   0..7      small scratch
//   7..31     weights: wqb 7..13, wob 13..15, wf1b 15..23, wf2b 23..31
//   31..67    qbuf   (QKV gemm -> attn)
//   67..103   kbuf   (QKV gemm -> attn)
//  103..139   vtb    (QKV gemm -> attn); THEN dbuf (outproj -> scatln)
//  139..175   regA:  lnseq (lnseq -> QKV gemm); then aout (attn -> outproj)
//   31..73.5  ln2bf  (scatln -> fc1)  [over dead qbuf+kbuf-head; disjoint from dbuf]
//   74..159   hbuf   (fc1 -> fc2)     [over dead kbuf-tail/dbuf/regA; disjoint from ln2bf]
// peak 175 MiB.

extern "C" void kernel_launch(void* const* d_in, const int* in_sizes, int n_in,
                              void* d_out, int out_size, void* d_ws, size_t ws_size,
                              hipStream_t stream) {
  const float* x    = (const float*)d_in[0];
  const float* lang = (const float*)d_in[1];
  const float* ln1w = (const float*)d_in[2];
  const float* ln1b = (const float*)d_in[3];
  const float* ln2w = (const float*)d_in[4];
  const float* ln2b = (const float*)d_in[5];
  const float* wqkv = (const float*)d_in[6];
  const float* bqkv = (const float*)d_in[7];
  const float* wout = (const float*)d_in[8];
  const float* bout = (const float*)d_in[9];
  const float* wfc1 = (const float*)d_in[10];
  const float* bfc1 = (const float*)d_in[11];
  const float* wfc2 = (const float*)d_in[12];
  const float* bfc2 = (const float*)d_in[13];
  float* out = (float*)d_out;
  char* ws = (char*)d_ws;
  const size_t MiB = 1ull << 20;

  float* lm      = (float*)(ws + 0 * MiB);
  float* score   = (float*)(ws + 1 * MiB);
  float* wall    = (float*)(ws + 2 * MiB);
  int*   rowmap  = (int*)  (ws + 3 * MiB);
  int*   selsrc  = (int*)  (ws + 4 * MiB);
  int*   lowlist = (int*)  (ws + 5 * MiB);
  float* lowtok  = (float*)(ws + 6 * MiB);
  u16* wqb  = (u16*)(ws + 7 * MiB);
  u16* wob  = (u16*)(ws + 13 * MiB);
  u16* wf1b = (u16*)(ws + 15 * MiB);
  u16* wf2b = (u16*)(ws + 23 * MiB);
  u16* qbuf = (u16*)(ws + 31 * MiB);
  u16* kbuf = (u16*)(ws + 67 * MiB);
  u16* vtb  = (u16*)(ws + 103 * MiB);
  u16* regA = (u16*)(ws + 139 * MiB);   // lnseq -> aout (36 MiB each, M1P rows)
  u16* lnseq = regA;
  u16* aout  = regA;
  u16* dbuf  = vtb;                     // outproj output; vtb dead after attn
  u16* ln2bf = qbuf;                    // 42.5 MiB (31..73.5); disjoint from dbuf
  u16* hbuf  = (u16*)(ws + 74 * MiB);   // 85 MiB (74..159); disjoint from ln2bf

  // weight conversion fp32 -> bf16
  {
    int n4;
    n4 = 3072 * 1024 / 4; k_f2bf4<<<(n4 + 255) / 256, 256, 0, stream>>>(wqkv, wqb, n4);
    n4 = 1024 * 1024 / 4; k_f2bf4<<<(n4 + 255) / 256, 256, 0, stream>>>(wout, wob, n4);
    n4 = 4096 * 1024 / 4; k_f2bf4<<<(n4 + 255) / 256, 256, 0, stream>>>(wfc1, wf1b, n4);
    n4 = 1024 * 4096 / 4; k_f2bf4<<<(n4 + 255) / 256, 256, 0, stream>>>(wfc2, wf2b, n4);
  }

  k_langmean<<<BB, 256, 0, stream>>>(lang, lm);
  k_score<<<NPATCH * BB, 256, 0, stream>>>(x, lm, score);
  k_select<<<BB, 1024, 0, stream>>>(score, wall, rowmap, selsrc, lowlist);
  k_lowtok<<<dim3(BB, 4), 256, 0, stream>>>(x, wall, lowlist, lowtok);
  k_lnseq<<<dim3(SP, BB), 256, 0, stream>>>(x, lowtok, selsrc, ln1w, ln1b, lnseq);

  {
    Epi e = {};
    e.bias = bqkv; e.qb = qbuf; e.kb = kbuf; e.vtb = vtb; e.mvalid = M1P;
    k_gemm6<0><<<dim3(M1P / 128, 3072 / 256), 256, 0, stream>>>(lnseq, 1024, wqb, 1024, 1024, e);
  }

  k_attn2<<<BB * 16 * NQC, 256, 0, stream>>>(qbuf, kbuf, vtb, aout);

  {
    Epi e = {};
    e.bias = bout; e.obf = dbuf; e.mvalid = M1P; e.ldc = 1024;
    k_gemm5<1><<<dim3(M1P / 128, 1024 / 128), 256, 0, stream>>>(aout, 1024, wob, 1024, 1024, e);
  }

  k_scatln<<<M2P, 256, 0, stream>>>(x, dbuf, rowmap, ln2w, ln2b, out, ln2bf);

  for (int c = 0; c < 2; c++) {
    Epi e2 = {};
    e2.bias = bfc1 + c * 2048; e2.obf = hbuf; e2.mvalid = M2P; e2.ldc = 2048;
    k_gemm6<2><<<dim3(M2P / 128, 2048 / 256), 256, 0, stream>>>(ln2bf, 1024, wf1b + (long)c * 2048 * 1024, 1024, 1024, e2);
    Epi e3 = {};
    e3.bias = (c == 0 ? bfc2 : nullptr); e3.of = out; e3.mvalid = M2;
    k_gemm5<3><<<dim3(M2P / 128, 1024 / 128), 256, 0, stream>>>(hbuf, 2048, wf2b + c * 2048, 4096, 2048, e3);
  }
}

// Round 11
// 1081.027 us; speedup vs baseline: 1.0196x; 1.0196x over previous
//
#include <hip/hip_runtime.h>
#include <hip/hip_bf16.h>

typedef unsigned short u16;
typedef __attribute__((ext_vector_type(4))) float f32x4;
typedef __attribute__((ext_vector_type(8))) short s16x8;

#define DEVI __device__ __forceinline__

static constexpr int NPATCH = 676;
static constexpr int KSEL   = 540;   // int(676*0.8)
static constexpr int NLOW   = 136;
static constexpr int BB     = 32;
static constexpr int CC     = 1024;
static constexpr int S      = 542;   // 1 + 540 + 1
static constexpr int SP     = 576;   // padded seq (9*64)
static constexpr int M1P    = SP * BB;     // 18432 rows, seq-major: m = b*SP + s
static constexpr int NTOK   = 677;
static constexpr int M2     = NTOK * BB;   // 21664
static constexpr int M2P    = 21760;       // pad to 128/256
static constexpr int MHALF  = 10880;       // M2P/2 (85*128)
static constexpr int NKT    = SP / 64;     // 9 kv tiles
static constexpr int NQC    = 5;           // q-chunks of 8 qtiles (36 qtiles total)

DEVI u16 f2bf(float f) {
  unsigned u = __float_as_uint(f);
  u += 0x7fffu + ((u >> 16) & 1u);
  return (u16)(u >> 16);
}
DEVI float bf2f(u16 h) { return __uint_as_float(((unsigned)h) << 16); }
DEVI float ex2(float x) { float r; asm("v_exp_f32 %0, %1" : "=v"(r) : "v"(x)); return r; }

DEVI void gld16(const void* g, void* l) {
  __builtin_amdgcn_global_load_lds((const __attribute__((address_space(1))) void*)g,
                                   (__attribute__((address_space(3))) void*)l,
                                   16, 0, 0);
}

DEVI void BAR() {
  asm volatile("" ::: "memory");
  __builtin_amdgcn_s_barrier();
  asm volatile("" ::: "memory");
}
#define VMC(N) asm volatile("s_waitcnt vmcnt(" #N ")" ::: "memory")

// ---------------- small kernels ----------------

__global__ void k_f2bf4(const float* __restrict__ in, u16* __restrict__ out, int n4) {
  int i = blockIdx.x * blockDim.x + threadIdx.x;
  if (i >= n4) return;
  float4 v = ((const float4*)in)[i];
  unsigned long long p = (unsigned long long)f2bf(v.x)
                       | ((unsigned long long)f2bf(v.y) << 16)
                       | ((unsigned long long)f2bf(v.z) << 32)
                       | ((unsigned long long)f2bf(v.w) << 48);
  *(unsigned long long*)&out[(long)i * 4] = p;
}

__global__ void k_langmean(const float* __restrict__ lang, float* __restrict__ lm) {
  int b = blockIdx.x, t = threadIdx.x;
  float a0 = 0, a1 = 0, a2 = 0, a3 = 0;
  for (int l = 0; l < 77; l++) {
    float4 v = ((const float4*)(lang + ((long)l * BB + b) * CC))[t];
    a0 += v.x; a1 += v.y; a2 += v.z; a3 += v.w;
  }
  const float inv = 1.f / 77.f;
  float4 o; o.x = a0 * inv; o.y = a1 * inv; o.z = a2 * inv; o.w = a3 * inv;
  ((float4*)(lm + b * CC))[t] = o;
}

__global__ void k_score(const float* __restrict__ x, const float* __restrict__ lm,
                        float* __restrict__ score) {
  int nb = blockIdx.x;
  int n = nb >> 5, b = nb & 31;
  int t = threadIdx.x;
  float4 xv = ((const float4*)(x + ((long)(n + 1) * BB + b) * CC))[t];
  float4 lv = ((const float4*)(lm + b * CC))[t];
  float s = xv.x * lv.x + xv.y * lv.y + xv.z * lv.z + xv.w * lv.w;
  for (int m = 1; m < 64; m <<= 1) s += __shfl_xor(s, m);
  __shared__ float sm[4];
  if ((t & 63) == 0) sm[t >> 6] = s;
  __syncthreads();
  if (t == 0) score[n * BB + b] = sm[0] + sm[1] + sm[2] + sm[3];
}

__global__ void k_select(const float* __restrict__ score, float* __restrict__ wall,
                         int* __restrict__ rowmap, int* __restrict__ selsrc,
                         int* __restrict__ lowlist) {
  int b = blockIdx.x, t = threadIdx.x;
  __shared__ float sc[NPATCH];
  __shared__ int hf[NPATCH];
  __shared__ float red[2];
  if (t < NPATCH) sc[t] = score[t * BB + b];
  __syncthreads();
  int high = 0;
  if (t < NPATCH) {
    float s = sc[t];
    int r = 0;
    for (int m = 0; m < NPATCH; m++) {
      float sm_ = sc[m];
      r += (sm_ > s) || (sm_ == s && m < t);
    }
    high = (r < KSEL);
    hf[t] = high;
  }
  __syncthreads();
  if (t < NPATCH) {
    int p = 0;
    for (int m = 0; m < t; m++) p += hf[m];
    if (high) {
      rowmap[b * NPATCH + t] = 1 + p;
      selsrc[b * S + 1 + p] = t + 1;        // row index into full x
    } else {
      rowmap[b * NPATCH + t] = S - 1;
      lowlist[b * NLOW + (t - p)] = t;
    }
  }
  if (t == 0) selsrc[b * S + 0] = 0;
  __syncthreads();
  if (t == 0) {
    float m = -3e38f;
    for (int i = 0; i < NPATCH; i++) if (!hf[i]) m = fmaxf(m, sc[i]);
    float d = 0;
    for (int i = 0; i < NPATCH; i++) if (!hf[i]) d += __expf(sc[i] - m);
    red[0] = m; red[1] = d;
  }
  __syncthreads();
  if (t < NPATCH) wall[b * NPATCH + t] = hf[t] ? 0.f : __expf(sc[t] - red[0]) / red[1];
}

__global__ void k_lowtok(const float* __restrict__ x, const float* __restrict__ wall,
                         const int* __restrict__ lowlist, float* __restrict__ lowtok) {
  int b = blockIdx.x, ch = blockIdx.y;
  int c = ch * 256 + threadIdx.x;
  float acc = 0.f;
  for (int i = 0; i < NLOW; i++) {
    int n = lowlist[b * NLOW + i];
    acc += wall[b * NPATCH + n] * x[((long)(n + 1) * BB + b) * CC + c];
  }
  lowtok[b * CC + c] = acc;
}

// gather + LayerNorm -> bf16 seq rows, SEQ-MAJOR: row = b*SP + s (pad rows zeroed)
__global__ void k_lnseq(const float* __restrict__ x, const float* __restrict__ lowtok,
                        const int* __restrict__ selsrc, const float* __restrict__ w,
                        const float* __restrict__ bias, u16* __restrict__ out) {
  int s = blockIdx.x, b = blockIdx.y, t = threadIdx.x;
  u16* orow = out + ((long)b * SP + s) * CC;
  if (s >= S) { *(unsigned long long*)&orow[4 * t] = 0ULL; return; }
  const float* src;
  if (s == 0)          src = x + (long)b * CC;
  else if (s == S - 1) src = lowtok + (long)b * CC;
  else                 src = x + ((long)selsrc[b * S + s] * BB + b) * CC;
  float4 v = ((const float4*)src)[t];
  float ss = v.x + v.y + v.z + v.w;
  float s2 = v.x * v.x + v.y * v.y + v.z * v.z + v.w * v.w;
  for (int k = 1; k < 64; k <<= 1) { ss += __shfl_xor(ss, k); s2 += __shfl_xor(s2, k); }
  __shared__ float sa[4], sb[4];
  if ((t & 63) == 0) { sa[t >> 6] = ss; sb[t >> 6] = s2; }
  __syncthreads();
  ss = sa[0] + sa[1] + sa[2] + sa[3];
  s2 = sb[0] + sb[1] + sb[2] + sb[3];
  float mu = ss * (1.f / CC);
  float var = s2 * (1.f / CC) - mu * mu;
  float rs = rsqrtf(var + 1e-5f);
  int c = 4 * t;
  unsigned long long p = (unsigned long long)f2bf((v.x - mu) * rs * w[c]     + bias[c])
                       | ((unsigned long long)f2bf((v.y - mu) * rs * w[c + 1] + bias[c + 1]) << 16)
                       | ((unsigned long long)f2bf((v.z - mu) * rs * w[c + 2] + bias[c + 2]) << 32)
                       | ((unsigned long long)f2bf((v.w - mu) * rs * w[c + 3] + bias[c + 3]) << 48);
  *(unsigned long long*)&orow[4 * t] = p;
}

// fused scatter (x + gathered d -> out fp32) + LayerNorm(out) -> bf16
__global__ void k_scatln(const float* __restrict__ x, const u16* __restrict__ dbuf,
                         const int* __restrict__ rowmap, const float* __restrict__ w,
                         const float* __restrict__ bias, float* __restrict__ out,
                         u16* __restrict__ lnout) {
  int m = blockIdx.x, t = threadIdx.x;
  u16* orow = lnout + (long)m * CC;
  if (m >= M2) { *(unsigned long long*)&orow[4 * t] = 0ULL; return; }
  int nf = m >> 5, b = m & 31;
  int srow = (nf == 0) ? 0 : rowmap[b * NPATCH + (nf - 1)];
  float4 xv = ((const float4*)(x + (long)m * CC))[t];
  unsigned long long dp = *(const unsigned long long*)&dbuf[((long)b * SP + srow) * CC + 4 * t];
  float4 v;
  v.x = xv.x + bf2f((u16)(dp));
  v.y = xv.y + bf2f((u16)(dp >> 16));
  v.z = xv.z + bf2f((u16)(dp >> 32));
  v.w = xv.w + bf2f((u16)(dp >> 48));
  ((float4*)(out + (long)m * CC))[t] = v;
  float ss = v.x + v.y + v.z + v.w;
  float s2 = v.x * v.x + v.y * v.y + v.z * v.z + v.w * v.w;
  for (int k = 1; k < 64; k <<= 1) { ss += __shfl_xor(ss, k); s2 += __shfl_xor(s2, k); }
  __shared__ float sa[4], sb[4];
  if ((t & 63) == 0) { sa[t >> 6] = ss; sb[t >> 6] = s2; }
  __syncthreads();
  ss = sa[0] + sa[1] + sa[2] + sa[3];
  s2 = sb[0] + sb[1] + sb[2] + sb[3];
  float mu = ss * (1.f / CC);
  float var = s2 * (1.f / CC) - mu * mu;
  float rs = rsqrtf(var + 1e-5f);
  int c = 4 * t;
  unsigned long long p = (unsigned long long)f2bf((v.x - mu) * rs * w[c]     + bias[c])
                       | ((unsigned long long)f2bf((v.y - mu) * rs * w[c + 1] + bias[c + 1]) << 16)
                       | ((unsigned long long)f2bf((v.z - mu) * rs * w[c + 2] + bias[c + 2]) << 32)
                       | ((unsigned long long)f2bf((v.w - mu) * rs * w[c + 3] + bias[c + 3]) << 48);
  *(unsigned long long*)&orow[4 * t] = p;
}

// ---------------- GEMM common ----------------

struct Epi {
  const float* bias;
  u16* obf;
  float* of;
  u16 *qb, *kb, *vtb;
  int mvalid, ldc;
};

// 128x32 K-step tile packed as 64 LDS-rows x 64 cols (8 KiB).
DEVI void stage32(u16* dst, const u16* src, int ld) {
  int t = threadIdx.x;
#pragma unroll
  for (int q = 0; q < 2; q++) {
    int s = t + q * 256;
    int R = s >> 3, clp = s & 7;
    int lc = clp ^ (R & 7);
    int m = 2 * R + (lc >> 2), kc = lc & 3;
    gld16(src + (long)m * ld + kc * 8, dst + s * 8);
  }
}

DEVI s16x8 frag32(const u16* tile, int m, int h4) {
  int R = m >> 1;
  int phys = ((((m & 1) << 2) | h4) ^ (R & 7));
  return *(const s16x8*)(tile + R * 64 + phys * 8);
}

// attn helpers (64-row x 64-col tiles, verified swizzle pair)
DEVI void stage64(u16* dst, const u16* src, int ld) {
  int t = threadIdx.x;
  int c = t & 7, r0 = t >> 3;             // rows 0..31
  gld16(src + (long)r0 * ld + ((c ^ (r0 & 7)) << 3), dst + t * 8);
  int r1 = r0 + 32;
  gld16(src + (long)r1 * ld + ((c ^ (r1 & 7)) << 3), dst + 2048 + t * 8);
}

DEVI s16x8 frag(const u16* half, int rh, int kk, int h4) {
  int chunk = ((kk << 2) | h4) ^ (rh & 7);
  return *(const s16x8*)(half + rh * 64 + chunk * 8);
}

// shared epilogue element-writer
template<int MODE>
DEVI void epi_store(const Epi& e, int m0, int n, const f32x4& a, float bias) {
  const float QSC = 0.125f * 1.44269504088896f;
  if (MODE == 0) {
    int part = n >> 10, cc = n & 1023;
    int hh = cc >> 6, dd = cc & 63;
    int b0 = m0 / SP, s0 = m0 % SP;
    if (part == 2) {
      u16 pk[4];
#pragma unroll
      for (int tt = 0; tt < 4; tt++) pk[tt] = f2bf(a[tt] + bias);
      *(unsigned long long*)&e.vtb[((long)(b0 * 16 + hh) * 64 + dd) * SP + s0] =
          *(unsigned long long*)pk;
    } else {
      u16* dst = (part == 0 ? e.qb : e.kb) + ((long)(b0 * 16 + hh) * SP + s0) * 64 + dd;
      float scl = (part == 0) ? QSC : 1.f;
#pragma unroll
      for (int tt = 0; tt < 4; tt++) dst[tt * 64] = f2bf((a[tt] + bias) * scl);
    }
  } else if (MODE == 1) {
#pragma unroll
    for (int tt = 0; tt < 4; tt++)
      e.obf[(long)(m0 + tt) * e.ldc + n] = f2bf(a[tt] + bias);
  } else if (MODE == 2) {
#pragma unroll
    for (int tt = 0; tt < 4; tt++) {
      float v = a[tt] + bias;
      v = v / (1.f + __expf(-1.702f * v));
      e.obf[(long)(m0 + tt) * e.ldc + n] = f2bf(v);
    }
  } else {
#pragma unroll
    for (int tt = 0; tt < 4; tt++) {
      int m = m0 + tt;
      if (m < e.mvalid) e.of[(long)m * CC + n] += a[tt] + bias;
    }
  }
}

// -- GEMM v5: 128x128 tile, BK=32, 3-buffer rotation, counted vmcnt (outproj/fc2) --

template<int MODE>
__global__ __launch_bounds__(256, 3) void k_gemm5(const u16* __restrict__ A, int lda,
                                                  const u16* __restrict__ Bw, int ldb,
                                                  int K, Epi e) {
  __shared__ __align__(16) u16 lds[3][2][4096];  // 48 KiB -> 3 blk/CU
  int t = threadIdx.x;
  int lane = t & 63, w = t >> 6;
  int h4 = lane >> 4, r = lane & 15;
  int wr = w >> 1, wc = w & 1;
  int MBk = gridDim.x, NBk = gridDim.y;
  int nwg = MBk * NBk;
  int orig = blockIdx.y * MBk + blockIdx.x;
  int q8 = nwg >> 3, r8 = nwg & 7, xcd = orig & 7, rk = orig >> 3;
  int wgid = (xcd < r8 ? xcd * (q8 + 1) : r8 * (q8 + 1) + (xcd - r8) * q8) + rk;
  int bm = wgid / NBk, bn = wgid % NBk;

  const u16* Asrc = A + (long)bm * 128 * lda;
  const u16* Bsrc = Bw + (long)bn * 128 * ldb;
  int NT = K >> 5;

  f32x4 acc[4][4];
#pragma unroll
  for (int i = 0; i < 4; i++)
#pragma unroll
    for (int j = 0; j < 4; j++) acc[i][j] = {0.f, 0.f, 0.f, 0.f};

  stage32(lds[0][0], Asrc, lda);
  stage32(lds[0][1], Bsrc, ldb);
  if (NT > 1) {
    stage32(lds[1][0], Asrc + 32, lda);
    stage32(lds[1][1], Bsrc + 32, ldb);
  }

  int bufr = 0, bufw = 2;
  for (int kt = 0; kt < NT; kt++) {
    if (kt + 1 < NT) { VMC(4); } else { VMC(0); }
    BAR();
    if (kt + 2 < NT) {
      stage32(lds[bufw][0], Asrc + (kt + 2) * 32, lda);
      stage32(lds[bufw][1], Bsrc + (kt + 2) * 32, ldb);
    }
    const u16* At = lds[bufr][0];
    const u16* Bt = lds[bufr][1];
    s16x8 af[4], bf[4];
#pragma unroll
    for (int i = 0; i < 4; i++) af[i] = frag32(At, wr * 64 + i * 16 + r, h4);
#pragma unroll
    for (int j = 0; j < 4; j++) bf[j] = frag32(Bt, wc * 64 + j * 16 + r, h4);
#pragma unroll
    for (int i = 0; i < 4; i++)
#pragma unroll
      for (int j = 0; j < 4; j++)
        acc[i][j] = __builtin_amdgcn_mfma_f32_16x16x32_bf16(af[i], bf[j], acc[i][j], 0, 0, 0);
    bufr = (bufr == 2) ? 0 : bufr + 1;
    bufw = (bufw == 2) ? 0 : bufw + 1;
  }

#pragma unroll
  for (int i = 0; i < 4; i++) {
    int m0 = bm * 128 + wr * 64 + i * 16 + 4 * h4;
#pragma unroll
    for (int j = 0; j < 4; j++) {
      int n = bn * 128 + wc * 64 + j * 16 + r;
      float bias = (MODE == 3 && e.bias == nullptr) ? 0.f : e.bias[n];
      epi_store<MODE>(e, m0, n, acc[i][j], bias);
    }
  }
}

// -- GEMM v6: 128x256 tile, BK=32, 2-buffer sync pipeline (QKV/fc1) --

template<int MODE>
__global__ __launch_bounds__(256, 2) void k_gemm6(const u16* __restrict__ A, int lda,
                                                  const u16* __restrict__ Bw, int ldb,
                                                  int K, Epi e) {
  __shared__ __align__(16) u16 lds[2][3][4096];  // [buf][A,B-lo,B-hi] = 48 KiB
  int t = threadIdx.x;
  int lane = t & 63, w = t >> 6;
  int h4 = lane >> 4, r = lane & 15;
  int wr = w >> 1, wc = w & 1;          // per-wave 64 rows x 128 cols
  int MBk = gridDim.x, NBk = gridDim.y;
  int nwg = MBk * NBk;
  int orig = blockIdx.y * MBk + blockIdx.x;
  int q8 = nwg >> 3, r8 = nwg & 7, xcd = orig & 7, rk = orig >> 3;
  int wgid = (xcd < r8 ? xcd * (q8 + 1) : r8 * (q8 + 1) + (xcd - r8) * q8) + rk;
  int bm = wgid / NBk, bn = wgid % NBk;

  const u16* Asrc = A + (long)bm * 128 * lda;
  const u16* Bsrc = Bw + (long)bn * 256 * ldb;
  int NT = K >> 5;

  f32x4 acc[4][8];
#pragma unroll
  for (int i = 0; i < 4; i++)
#pragma unroll
    for (int j = 0; j < 8; j++) acc[i][j] = {0.f, 0.f, 0.f, 0.f};

  stage32(lds[0][0], Asrc, lda);
  stage32(lds[0][1], Bsrc, ldb);
  stage32(lds[0][2], Bsrc + (long)128 * ldb, ldb);
  __syncthreads();

  for (int kt = 0; kt < NT; kt++) {
    int cur = kt & 1;
    if (kt + 1 < NT) {
      stage32(lds[cur ^ 1][0], Asrc + (kt + 1) * 32, lda);
      stage32(lds[cur ^ 1][1], Bsrc + (kt + 1) * 32, ldb);
      stage32(lds[cur ^ 1][2], Bsrc + (long)128 * ldb + (kt + 1) * 32, ldb);
    }
    const u16* At = lds[cur][0];
    const u16* Bt = lds[cur][1 + wc];   // wc=0 -> n 0..127, wc=1 -> n 128..255
    s16x8 af[4], bf[8];
#pragma unroll
    for (int i = 0; i < 4; i++) af[i] = frag32(At, wr * 64 + i * 16 + r, h4);
#pragma unroll
    for (int j = 0; j < 8; j++) bf[j] = frag32(Bt, j * 16 + r, h4);
#pragma unroll
    for (int i = 0; i < 4; i++)
#pragma unroll
      for (int j = 0; j < 8; j++)
        acc[i][j] = __builtin_amdgcn_mfma_f32_16x16x32_bf16(af[i], bf[j], acc[i][j], 0, 0, 0);
    __syncthreads();   // drains vmcnt (next-tile stages) + syncs LDS reuse
  }

#pragma unroll
  for (int i = 0; i < 4; i++) {
    int m0 = bm * 128 + wr * 64 + i * 16 + 4 * h4;
#pragma unroll
    for (int j = 0; j < 8; j++) {
      int n = bn * 256 + wc * 128 + j * 16 + r;
      float bias = (MODE == 3 && e.bias == nullptr) ? 0.f : e.bias[n];
      epi_store<MODE>(e, m0, n, acc[i][j], bias);
    }
  }
}

// ---------------- flash attention v2: LDS-staged KV, 2-phase pipeline ----------------

__global__ __launch_bounds__(256, 4) void k_attn2(const u16* __restrict__ qb,
                                                  const u16* __restrict__ kb,
                                                  const u16* __restrict__ vtb,
                                                  u16* __restrict__ aout) {
  __shared__ __align__(16) u16 Kt[2][4096];
  __shared__ __align__(16) u16 Vt[2][4096];
  __shared__ __align__(16) u16 Pl[4][1024];

  int nwg = gridDim.x;                   // 2560
  int orig = blockIdx.x;
  int q8 = nwg >> 3, r8 = nwg & 7, xcd = orig & 7, rk = orig >> 3;
  int wgid = (xcd < r8 ? xcd * (q8 + 1) : r8 * (q8 + 1) + (xcd - r8) * q8) + rk;
  int bh = wgid / NQC, qc = wgid % NQC;  // all q-chunks of a (b,h) contiguous -> same XCD
  int b = bh >> 4, hh = bh & 15;
  int t = threadIdx.x, w = t >> 6, lane = t & 63;
  int h4 = lane >> 4, r = lane & 15;

  const u16* Q  = qb  + (long)bh * SP * 64;
  const u16* Kg = kb  + (long)bh * SP * 64;
  const u16* Vg = vtb + (long)bh * 64 * SP;

  int qt[2];
  bool act[2];
  s16x8 aq0[2], aq1[2];
  f32x4 o[2][4];
  float mM[2][4], lL[2][4];
#pragma unroll
  for (int sub = 0; sub < 2; sub++) {
    qt[sub] = qc * 8 + w * 2 + sub;
    act[sub] = qt[sub] < SP / 16;
    if (act[sub]) {
      aq0[sub] = *(const s16x8*)&Q[(qt[sub] * 16 + r) * 64 + h4 * 8];
      aq1[sub] = *(const s16x8*)&Q[(qt[sub] * 16 + r) * 64 + 32 + h4 * 8];
    }
#pragma unroll
    for (int i = 0; i < 4; i++) { o[sub][i] = {0.f, 0.f, 0.f, 0.f}; mM[sub][i] = -1e30f; lL[sub][i] = 0.f; }
  }

  // prologue: stage tile 0
  stage64(Kt[0], Kg, 64);
  stage64(Vt[0], Vg, SP);
  VMC(0);
  BAR();

  for (int kt = 0; kt < NKT; kt++) {
    int cur = kt & 1;
    if (kt + 1 < NKT) {                 // issue next-tile loads (other buffer)
      stage64(Kt[cur ^ 1], Kg + (kt + 1) * 64 * 64, 64);
      stage64(Vt[cur ^ 1], Vg + (kt + 1) * 64, SP);
    }
    int kv0 = kt * 64;
    const u16* Kc = Kt[cur];
    const u16* Vc = Vt[cur];
#pragma unroll
    for (int sub = 0; sub < 2; sub++) {
      if (!act[sub]) continue;
      // ---- QK^T: S[q16][kv64]
      f32x4 sf[4];
#pragma unroll
      for (int f = 0; f < 4; f++) {
        sf[f] = {0.f, 0.f, 0.f, 0.f};
        sf[f] = __builtin_amdgcn_mfma_f32_16x16x32_bf16(aq0[sub], frag(Kc, f * 16 + r, 0, h4), sf[f], 0, 0, 0);
        sf[f] = __builtin_amdgcn_mfma_f32_16x16x32_bf16(aq1[sub], frag(Kc, f * 16 + r, 1, h4), sf[f], 0, 0, 0);
      }
      if (kv0 + 64 > S) {               // mask invalid kv columns
#pragma unroll
        for (int f = 0; f < 4; f++)
          if (kv0 + f * 16 + r >= S) {
#pragma unroll
            for (int tt = 0; tt < 4; tt++) sf[f][tt] = -1e30f;
          }
      }
      // ---- online softmax (base-2; Q pre-scaled by 0.125*log2e)
      float mx[4];
#pragma unroll
      for (int tt = 0; tt < 4; tt++)
        mx[tt] = fmaxf(fmaxf(sf[0][tt], sf[1][tt]), fmaxf(sf[2][tt], sf[3][tt]));
      for (int msk = 1; msk < 16; msk <<= 1) {
#pragma unroll
        for (int tt = 0; tt < 4; tt++) mx[tt] = fmaxf(mx[tt], __shfl_xor(mx[tt], msk));
      }
      int need = 0;
#pragma unroll
      for (int tt = 0; tt < 4; tt++) need |= (mx[tt] > mM[sub][tt] + 8.f);
      if (__any(need)) {                // rescale path (rare after first tile)
#pragma unroll
        for (int tt = 0; tt < 4; tt++) {
          float mn = fmaxf(mM[sub][tt], mx[tt]);
          float sc = ex2(mM[sub][tt] - mn);
          mM[sub][tt] = mn;
          lL[sub][tt] *= sc;
#pragma unroll
          for (int nf = 0; nf < 4; nf++) o[sub][nf][tt] *= sc;
        }
      }
      float rs[4];
#pragma unroll
      for (int tt = 0; tt < 4; tt++) {
        float m_ = mM[sub][tt];
        float p0 = ex2(sf[0][tt] - m_), p1 = ex2(sf[1][tt] - m_);
        float p2 = ex2(sf[2][tt] - m_), p3 = ex2(sf[3][tt] - m_);
        sf[0][tt] = p0; sf[1][tt] = p1; sf[2][tt] = p2; sf[3][tt] = p3;
        rs[tt] = (p0 + p1) + (p2 + p3);
      }
      for (int msk = 1; msk < 16; msk <<= 1) {
#pragma unroll
        for (int tt = 0; tt < 4; tt++) rs[tt] += __shfl_xor(rs[tt], msk);
      }
#pragma unroll
      for (int tt = 0; tt < 4; tt++) lL[sub][tt] += rs[tt];
      // ---- pack P -> LDS (round-to-nearest bf16), chunk-swizzled rows
      u16* Pw = Pl[w];
#pragma unroll
      for (int f = 0; f < 4; f++)
#pragma unroll
        for (int tt = 0; tt < 4; tt++) {
          int q = 4 * h4 + tt;
          int chunk = (f * 2 + (r >> 3)) ^ (q & 7);
          Pw[q * 64 + chunk * 8 + (r & 7)] = f2bf(sf[f][tt]);
        }
      // ---- PV
      s16x8 pa0 = frag(Pw, r, 0, h4);
      s16x8 pa1 = frag(Pw, r, 1, h4);
#pragma unroll
      for (int nf = 0; nf < 4; nf++) {
        o[sub][nf] = __builtin_amdgcn_mfma_f32_16x16x32_bf16(pa0, frag(Vc, nf * 16 + r, 0, h4), o[sub][nf], 0, 0, 0);
        o[sub][nf] = __builtin_amdgcn_mfma_f32_16x16x32_bf16(pa1, frag(Vc, nf * 16 + r, 1, h4), o[sub][nf], 0, 0, 0);
      }
    }
    VMC(0);
    BAR();
  }

  // ---- write output
#pragma unroll
  for (int sub = 0; sub < 2; sub++) {
    if (!act[sub]) continue;
    float inv[4];
#pragma unroll
    for (int tt = 0; tt < 4; tt++) inv[tt] = 1.f / lL[sub][tt];
#pragma unroll
    for (int nf = 0; nf < 4; nf++)
#pragma unroll
      for (int tt = 0; tt < 4; tt++) {
        int q = qt[sub] * 16 + 4 * h4 + tt;
        if (q < S) aout[((long)b * SP + q) * CC + hh * 64 + nf * 16 + r] = f2bf(o[sub][nf][tt] * inv[tt]);
      }
  }
}

// ---------------- launcher ----------------
// ws liveness map (MiB):
//   0..7      small scratch
//   7..31     weights: wqb 7..13, wob 13..15, wf1b 15..23, wf2b 23..31
//   31..67    qbuf   (QKV gemm -> attn)
//   67..103   kbuf   (QKV gemm -> attn)
//  103..139   vtb    (QKV gemm -> attn); THEN dbuf (outproj -> scatln)
//  139..175   regA:  lnseq (lnseq -> QKV gemm); then aout (attn -> outproj)
//   31..73.5  ln2bf  (scatln -> fc1)  [over dead qbuf+kbuf-head; disjoint from dbuf]
//   74..159   hbuf   (fc1 chunk -> fc2 chunk) [MHALF x 4096 bf16 = 85 MiB; over dead
//                                              dbuf/regA; disjoint from ln2bf]
// peak 175 MiB.

extern "C" void kernel_launch(void* const* d_in, const int* in_sizes, int n_in,
                              void* d_out, int out_size, void* d_ws, size_t ws_size,
                              hipStream_t stream) {
  const float* x    = (const float*)d_in[0];
  const float* lang = (const float*)d_in[1];
  const float* ln1w = (const float*)d_in[2];
  const float* ln1b = (const float*)d_in[3];
  const float* ln2w = (const float*)d_in[4];
  const float* ln2b = (const float*)d_in[5];
  const float* wqkv = (const float*)d_in[6];
  const float* bqkv = (const float*)d_in[7];
  const float* wout = (const float*)d_in[8];
  const float* bout = (const float*)d_in[9];
  const float* wfc1 = (const float*)d_in[10];
  const float* bfc1 = (const float*)d_in[11];
  const float* wfc2 = (const float*)d_in[12];
  const float* bfc2 = (const float*)d_in[13];
  float* out = (float*)d_out;
  char* ws = (char*)d_ws;
  const size_t MiB = 1ull << 20;

  float* lm      = (float*)(ws + 0 * MiB);
  float* score   = (float*)(ws + 1 * MiB);
  float* wall    = (float*)(ws + 2 * MiB);
  int*   rowmap  = (int*)  (ws + 3 * MiB);
  int*   selsrc  = (int*)  (ws + 4 * MiB);
  int*   lowlist = (int*)  (ws + 5 * MiB);
  float* lowtok  = (float*)(ws + 6 * MiB);
  u16* wqb  = (u16*)(ws + 7 * MiB);
  u16* wob  = (u16*)(ws + 13 * MiB);
  u16* wf1b = (u16*)(ws + 15 * MiB);
  u16* wf2b = (u16*)(ws + 23 * MiB);
  u16* qbuf = (u16*)(ws + 31 * MiB);
  u16* kbuf = (u16*)(ws + 67 * MiB);
  u16* vtb  = (u16*)(ws + 103 * MiB);
  u16* regA = (u16*)(ws + 139 * MiB);   // lnseq -> aout (36 MiB each, M1P rows)
  u16* lnseq = regA;
  u16* aout  = regA;
  u16* dbuf  = vtb;                     // outproj output; vtb dead after attn
  u16* ln2bf = qbuf;                    // 42.5 MiB (31..73.5); disjoint from dbuf
  u16* hbuf  = (u16*)(ws + 74 * MiB);   // 85 MiB (74..159); disjoint from ln2bf

  // weight conversion fp32 -> bf16
  {
    int n4;
    n4 = 3072 * 1024 / 4; k_f2bf4<<<(n4 + 255) / 256, 256, 0, stream>>>(wqkv, wqb, n4);
    n4 = 1024 * 1024 / 4; k_f2bf4<<<(n4 + 255) / 256, 256, 0, stream>>>(wout, wob, n4);
    n4 = 4096 * 1024 / 4; k_f2bf4<<<(n4 + 255) / 256, 256, 0, stream>>>(wfc1, wf1b, n4);
    n4 = 1024 * 4096 / 4; k_f2bf4<<<(n4 + 255) / 256, 256, 0, stream>>>(wfc2, wf2b, n4);
  }

  k_langmean<<<BB, 256, 0, stream>>>(lang, lm);
  k_score<<<NPATCH * BB, 256, 0, stream>>>(x, lm, score);
  k_select<<<BB, 1024, 0, stream>>>(score, wall, rowmap, selsrc, lowlist);
  k_lowtok<<<dim3(BB, 4), 256, 0, stream>>>(x, wall, lowlist, lowtok);
  k_lnseq<<<dim3(SP, BB), 256, 0, stream>>>(x, lowtok, selsrc, ln1w, ln1b, lnseq);

  {
    Epi e = {};
    e.bias = bqkv; e.qb = qbuf; e.kb = kbuf; e.vtb = vtb; e.mvalid = M1P;
    k_gemm6<0><<<dim3(M1P / 128, 3072 / 256), 256, 0, stream>>>(lnseq, 1024, wqb, 1024, 1024, e);
  }

  k_attn2<<<BB * 16 * NQC, 256, 0, stream>>>(qbuf, kbuf, vtb, aout);

  {
    Epi e = {};
    e.bias = bout; e.obf = dbuf; e.mvalid = M1P; e.ldc = 1024;
    k_gemm5<1><<<dim3(M1P / 128, 1024 / 128), 256, 0, stream>>>(aout, 1024, wob, 1024, 1024, e);
  }

  k_scatln<<<M2P, 256, 0, stream>>>(x, dbuf, rowmap, ln2w, ln2b, out, ln2bf);

  // MLP: M-split into two row-halves; per half, fc1 over full hidden (N=4096,
  // ldc=4096 into hbuf) then fc2 as a single K=4096 pass -> ONE fp32 RMW of out.
  for (int mc = 0; mc < 2; mc++) {
    int rvalid = (mc == 0) ? MHALF : (M2 - MHALF);   // 10880, 10784
    Epi e2 = {};
    e2.bias = bfc1; e2.obf = hbuf; e2.mvalid = MHALF; e2.ldc = 4096;
    k_gemm6<2><<<dim3(MHALF / 128, 4096 / 256), 256, 0, stream>>>(
        ln2bf + (long)mc * MHALF * 1024, 1024, wf1b, 1024, 1024, e2);
    Epi e3 = {};
    e3.bias = bfc2; e3.of = out + (long)mc * MHALF * CC; e3.mvalid = rvalid;
    k_gemm5<3><<<dim3(MHALF / 128, 1024 / 128), 256, 0, stream>>>(
        hbuf, 4096, wf2b, 4096, 4096, e3);
  }
}

// Round 12
// 1024.234 us; speedup vs baseline: 1.0761x; 1.0554x over previous
//
#include <hip/hip_runtime.h>
#include <hip/hip_bf16.h>

typedef unsigned short u16;
typedef __attribute__((ext_vector_type(4))) float f32x4;
typedef __attribute__((ext_vector_type(8))) short s16x8;

#define DEVI __device__ __forceinline__

static constexpr int NPATCH = 676;
static constexpr int KSEL   = 540;   // int(676*0.8)
static constexpr int NLOW   = 136;
static constexpr int BB     = 32;
static constexpr int CC     = 1024;
static constexpr int S      = 542;   // 1 + 540 + 1
static constexpr int SP     = 576;   // padded seq (9*64)
static constexpr int M1P    = SP * BB;     // 18432 rows, seq-major: m = b*SP + s
static constexpr int NTOK   = 677;
static constexpr int M2     = NTOK * BB;   // 21664
static constexpr int M2P    = 21760;       // pad to 128/256
static constexpr int MHALF  = 10880;       // M2P/2 (85*128)
static constexpr int NKT    = SP / 64;     // 9 kv tiles
static constexpr int NQC    = 5;           // q-chunks of 8 qtiles (36 qtiles total)

DEVI u16 f2bf(float f) {
  unsigned u = __float_as_uint(f);
  u += 0x7fffu + ((u >> 16) & 1u);
  return (u16)(u >> 16);
}
DEVI float bf2f(u16 h) { return __uint_as_float(((unsigned)h) << 16); }
DEVI float ex2(float x) { float r; asm("v_exp_f32 %0, %1" : "=v"(r) : "v"(x)); return r; }

DEVI void gld16(const void* g, void* l) {
  __builtin_amdgcn_global_load_lds((const __attribute__((address_space(1))) void*)g,
                                   (__attribute__((address_space(3))) void*)l,
                                   16, 0, 0);
}

DEVI void BAR() {
  asm volatile("" ::: "memory");
  __builtin_amdgcn_s_barrier();
  asm volatile("" ::: "memory");
}
#define VMC(N) asm volatile("s_waitcnt vmcnt(" #N ")" ::: "memory")

// ---------------- small kernels ----------------

__global__ void k_f2bf4(const float* __restrict__ in, u16* __restrict__ out, int n4) {
  int i = blockIdx.x * blockDim.x + threadIdx.x;
  if (i >= n4) return;
  float4 v = ((const float4*)in)[i];
  unsigned long long p = (unsigned long long)f2bf(v.x)
                       | ((unsigned long long)f2bf(v.y) << 16)
                       | ((unsigned long long)f2bf(v.z) << 32)
                       | ((unsigned long long)f2bf(v.w) << 48);
  *(unsigned long long*)&out[(long)i * 4] = p;
}

__global__ void k_langmean(const float* __restrict__ lang, float* __restrict__ lm) {
  int b = blockIdx.x, t = threadIdx.x;
  float a0 = 0, a1 = 0, a2 = 0, a3 = 0;
  for (int l = 0; l < 77; l++) {
    float4 v = ((const float4*)(lang + ((long)l * BB + b) * CC))[t];
    a0 += v.x; a1 += v.y; a2 += v.z; a3 += v.w;
  }
  const float inv = 1.f / 77.f;
  float4 o; o.x = a0 * inv; o.y = a1 * inv; o.z = a2 * inv; o.w = a3 * inv;
  ((float4*)(lm + b * CC))[t] = o;
}

__global__ void k_score(const float* __restrict__ x, const float* __restrict__ lm,
                        float* __restrict__ score) {
  int nb = blockIdx.x;
  int n = nb >> 5, b = nb & 31;
  int t = threadIdx.x;
  float4 xv = ((const float4*)(x + ((long)(n + 1) * BB + b) * CC))[t];
  float4 lv = ((const float4*)(lm + b * CC))[t];
  float s = xv.x * lv.x + xv.y * lv.y + xv.z * lv.z + xv.w * lv.w;
  for (int m = 1; m < 64; m <<= 1) s += __shfl_xor(s, m);
  __shared__ float sm[4];
  if ((t & 63) == 0) sm[t >> 6] = s;
  __syncthreads();
  if (t == 0) score[n * BB + b] = sm[0] + sm[1] + sm[2] + sm[3];
}

__global__ void k_select(const float* __restrict__ score, float* __restrict__ wall,
                         int* __restrict__ rowmap, int* __restrict__ selsrc,
                         int* __restrict__ lowlist) {
  int b = blockIdx.x, t = threadIdx.x;
  __shared__ float sc[NPATCH];
  __shared__ int hf[NPATCH];
  __shared__ float red[2];
  if (t < NPATCH) sc[t] = score[t * BB + b];
  __syncthreads();
  int high = 0;
  if (t < NPATCH) {
    float s = sc[t];
    int r = 0;
    for (int m = 0; m < NPATCH; m++) {
      float sm_ = sc[m];
      r += (sm_ > s) || (sm_ == s && m < t);
    }
    high = (r < KSEL);
    hf[t] = high;
  }
  __syncthreads();
  if (t < NPATCH) {
    int p = 0;
    for (int m = 0; m < t; m++) p += hf[m];
    if (high) {
      rowmap[b * NPATCH + t] = 1 + p;
      selsrc[b * S + 1 + p] = t + 1;        // row index into full x
    } else {
      rowmap[b * NPATCH + t] = S - 1;
      lowlist[b * NLOW + (t - p)] = t;
    }
  }
  if (t == 0) selsrc[b * S + 0] = 0;
  __syncthreads();
  if (t == 0) {
    float m = -3e38f;
    for (int i = 0; i < NPATCH; i++) if (!hf[i]) m = fmaxf(m, sc[i]);
    float d = 0;
    for (int i = 0; i < NPATCH; i++) if (!hf[i]) d += __expf(sc[i] - m);
    red[0] = m; red[1] = d;
  }
  __syncthreads();
  if (t < NPATCH) wall[b * NPATCH + t] = hf[t] ? 0.f : __expf(sc[t] - red[0]) / red[1];
}

__global__ void k_lowtok(const float* __restrict__ x, const float* __restrict__ wall,
                         const int* __restrict__ lowlist, float* __restrict__ lowtok) {
  int b = blockIdx.x, ch = blockIdx.y;
  int c = ch * 256 + threadIdx.x;
  float acc = 0.f;
  for (int i = 0; i < NLOW; i++) {
    int n = lowlist[b * NLOW + i];
    acc += wall[b * NPATCH + n] * x[((long)(n + 1) * BB + b) * CC + c];
  }
  lowtok[b * CC + c] = acc;
}

// gather + LayerNorm -> bf16 seq rows, SEQ-MAJOR: row = b*SP + s (pad rows zeroed)
__global__ void k_lnseq(const float* __restrict__ x, const float* __restrict__ lowtok,
                        const int* __restrict__ selsrc, const float* __restrict__ w,
                        const float* __restrict__ bias, u16* __restrict__ out) {
  int s = blockIdx.x, b = blockIdx.y, t = threadIdx.x;
  u16* orow = out + ((long)b * SP + s) * CC;
  if (s >= S) { *(unsigned long long*)&orow[4 * t] = 0ULL; return; }
  const float* src;
  if (s == 0)          src = x + (long)b * CC;
  else if (s == S - 1) src = lowtok + (long)b * CC;
  else                 src = x + ((long)selsrc[b * S + s] * BB + b) * CC;
  float4 v = ((const float4*)src)[t];
  float ss = v.x + v.y + v.z + v.w;
  float s2 = v.x * v.x + v.y * v.y + v.z * v.z + v.w * v.w;
  for (int k = 1; k < 64; k <<= 1) { ss += __shfl_xor(ss, k); s2 += __shfl_xor(s2, k); }
  __shared__ float sa[4], sb[4];
  if ((t & 63) == 0) { sa[t >> 6] = ss; sb[t >> 6] = s2; }
  __syncthreads();
  ss = sa[0] + sa[1] + sa[2] + sa[3];
  s2 = sb[0] + sb[1] + sb[2] + sb[3];
  float mu = ss * (1.f / CC);
  float var = s2 * (1.f / CC) - mu * mu;
  float rs = rsqrtf(var + 1e-5f);
  int c = 4 * t;
  unsigned long long p = (unsigned long long)f2bf((v.x - mu) * rs * w[c]     + bias[c])
                       | ((unsigned long long)f2bf((v.y - mu) * rs * w[c + 1] + bias[c + 1]) << 16)
                       | ((unsigned long long)f2bf((v.z - mu) * rs * w[c + 2] + bias[c + 2]) << 32)
                       | ((unsigned long long)f2bf((v.w - mu) * rs * w[c + 3] + bias[c + 3]) << 48);
  *(unsigned long long*)&orow[4 * t] = p;
}

// fused scatter (x + gathered d -> out fp32) + LayerNorm(out) -> bf16
__global__ void k_scatln(const float* __restrict__ x, const u16* __restrict__ dbuf,
                         const int* __restrict__ rowmap, const float* __restrict__ w,
                         const float* __restrict__ bias, float* __restrict__ out,
                         u16* __restrict__ lnout) {
  int m = blockIdx.x, t = threadIdx.x;
  u16* orow = lnout + (long)m * CC;
  if (m >= M2) { *(unsigned long long*)&orow[4 * t] = 0ULL; return; }
  int nf = m >> 5, b = m & 31;
  int srow = (nf == 0) ? 0 : rowmap[b * NPATCH + (nf - 1)];
  float4 xv = ((const float4*)(x + (long)m * CC))[t];
  unsigned long long dp = *(const unsigned long long*)&dbuf[((long)b * SP + srow) * CC + 4 * t];
  float4 v;
  v.x = xv.x + bf2f((u16)(dp));
  v.y = xv.y + bf2f((u16)(dp >> 16));
  v.z = xv.z + bf2f((u16)(dp >> 32));
  v.w = xv.w + bf2f((u16)(dp >> 48));
  ((float4*)(out + (long)m * CC))[t] = v;
  float ss = v.x + v.y + v.z + v.w;
  float s2 = v.x * v.x + v.y * v.y + v.z * v.z + v.w * v.w;
  for (int k = 1; k < 64; k <<= 1) { ss += __shfl_xor(ss, k); s2 += __shfl_xor(s2, k); }
  __shared__ float sa[4], sb[4];
  if ((t & 63) == 0) { sa[t >> 6] = ss; sb[t >> 6] = s2; }
  __syncthreads();
  ss = sa[0] + sa[1] + sa[2] + sa[3];
  s2 = sb[0] + sb[1] + sb[2] + sb[3];
  float mu = ss * (1.f / CC);
  float var = s2 * (1.f / CC) - mu * mu;
  float rs = rsqrtf(var + 1e-5f);
  int c = 4 * t;
  unsigned long long p = (unsigned long long)f2bf((v.x - mu) * rs * w[c]     + bias[c])
                       | ((unsigned long long)f2bf((v.y - mu) * rs * w[c + 1] + bias[c + 1]) << 16)
                       | ((unsigned long long)f2bf((v.z - mu) * rs * w[c + 2] + bias[c + 2]) << 32)
                       | ((unsigned long long)f2bf((v.w - mu) * rs * w[c + 3] + bias[c + 3]) << 48);
  *(unsigned long long*)&orow[4 * t] = p;
}

// ---------------- GEMM common ----------------

struct Epi {
  const float* bias;
  u16* obf;
  float* of;
  u16 *qb, *kb, *vtb;
  int mvalid, ldc;
};

// 128x32 K-step tile packed as 64 LDS-rows x 64 cols (8 KiB).
DEVI void stage32(u16* dst, const u16* src, int ld) {
  int t = threadIdx.x;
#pragma unroll
  for (int q = 0; q < 2; q++) {
    int s = t + q * 256;
    int R = s >> 3, clp = s & 7;
    int lc = clp ^ (R & 7);
    int m = 2 * R + (lc >> 2), kc = lc & 3;
    gld16(src + (long)m * ld + kc * 8, dst + s * 8);
  }
}

DEVI s16x8 frag32(const u16* tile, int m, int h4) {
  int R = m >> 1;
  int phys = ((((m & 1) << 2) | h4) ^ (R & 7));
  return *(const s16x8*)(tile + R * 64 + phys * 8);
}

// attn helpers (64-row x 64-col tiles, verified swizzle pair)
DEVI void stage64(u16* dst, const u16* src, int ld) {
  int t = threadIdx.x;
  int c = t & 7, r0 = t >> 3;             // rows 0..31
  gld16(src + (long)r0 * ld + ((c ^ (r0 & 7)) << 3), dst + t * 8);
  int r1 = r0 + 32;
  gld16(src + (long)r1 * ld + ((c ^ (r1 & 7)) << 3), dst + 2048 + t * 8);
}

DEVI s16x8 frag(const u16* half, int rh, int kk, int h4) {
  int chunk = ((kk << 2) | h4) ^ (rh & 7);
  return *(const s16x8*)(half + rh * 64 + chunk * 8);
}

// shared epilogue element-writer
template<int MODE>
DEVI void epi_store(const Epi& e, int m0, int n, const f32x4& a, float bias) {
  const float QSC = 0.125f * 1.44269504088896f;
  if (MODE == 0) {
    int part = n >> 10, cc = n & 1023;
    int hh = cc >> 6, dd = cc & 63;
    int b0 = m0 / SP, s0 = m0 % SP;
    if (part == 2) {
      u16 pk[4];
#pragma unroll
      for (int tt = 0; tt < 4; tt++) pk[tt] = f2bf(a[tt] + bias);
      *(unsigned long long*)&e.vtb[((long)(b0 * 16 + hh) * 64 + dd) * SP + s0] =
          *(unsigned long long*)pk;
    } else {
      u16* dst = (part == 0 ? e.qb : e.kb) + ((long)(b0 * 16 + hh) * SP + s0) * 64 + dd;
      float scl = (part == 0) ? QSC : 1.f;
#pragma unroll
      for (int tt = 0; tt < 4; tt++) dst[tt * 64] = f2bf((a[tt] + bias) * scl);
    }
  } else if (MODE == 1) {
#pragma unroll
    for (int tt = 0; tt < 4; tt++)
      e.obf[(long)(m0 + tt) * e.ldc + n] = f2bf(a[tt] + bias);
  } else if (MODE == 2) {
#pragma unroll
    for (int tt = 0; tt < 4; tt++) {
      float v = a[tt] + bias;
      v = v / (1.f + __expf(-1.702f * v));
      e.obf[(long)(m0 + tt) * e.ldc + n] = f2bf(v);
    }
  } else {
#pragma unroll
    for (int tt = 0; tt < 4; tt++) {
      int m = m0 + tt;
      if (m < e.mvalid) e.of[(long)m * CC + n] += a[tt] + bias;
    }
  }
}

// -- GEMM v5: 128x128 tile, BK=32, 3-buffer rotation, counted vmcnt (outproj/fc2) --

template<int MODE>
__global__ __launch_bounds__(256, 3) void k_gemm5(const u16* __restrict__ A, int lda,
                                                  const u16* __restrict__ Bw, int ldb,
                                                  int K, Epi e) {
  __shared__ __align__(16) u16 lds[3][2][4096];  // 48 KiB -> 3 blk/CU
  int t = threadIdx.x;
  int lane = t & 63, w = t >> 6;
  int h4 = lane >> 4, r = lane & 15;
  int wr = w >> 1, wc = w & 1;
  int MBk = gridDim.x, NBk = gridDim.y;
  int nwg = MBk * NBk;
  int orig = blockIdx.y * MBk + blockIdx.x;
  int q8 = nwg >> 3, r8 = nwg & 7, xcd = orig & 7, rk = orig >> 3;
  int wgid = (xcd < r8 ? xcd * (q8 + 1) : r8 * (q8 + 1) + (xcd - r8) * q8) + rk;
  int bm = wgid / NBk, bn = wgid % NBk;

  const u16* Asrc = A + (long)bm * 128 * lda;
  const u16* Bsrc = Bw + (long)bn * 128 * ldb;
  int NT = K >> 5;

  f32x4 acc[4][4];
#pragma unroll
  for (int i = 0; i < 4; i++)
#pragma unroll
    for (int j = 0; j < 4; j++) acc[i][j] = {0.f, 0.f, 0.f, 0.f};

  stage32(lds[0][0], Asrc, lda);
  stage32(lds[0][1], Bsrc, ldb);
  if (NT > 1) {
    stage32(lds[1][0], Asrc + 32, lda);
    stage32(lds[1][1], Bsrc + 32, ldb);
  }

  int bufr = 0, bufw = 2;
  for (int kt = 0; kt < NT; kt++) {
    if (kt + 1 < NT) { VMC(4); } else { VMC(0); }
    BAR();
    if (kt + 2 < NT) {
      stage32(lds[bufw][0], Asrc + (kt + 2) * 32, lda);
      stage32(lds[bufw][1], Bsrc + (kt + 2) * 32, ldb);
    }
    const u16* At = lds[bufr][0];
    const u16* Bt = lds[bufr][1];
    s16x8 af[4], bf[4];
#pragma unroll
    for (int i = 0; i < 4; i++) af[i] = frag32(At, wr * 64 + i * 16 + r, h4);
#pragma unroll
    for (int j = 0; j < 4; j++) bf[j] = frag32(Bt, wc * 64 + j * 16 + r, h4);
#pragma unroll
    for (int i = 0; i < 4; i++)
#pragma unroll
      for (int j = 0; j < 4; j++)
        acc[i][j] = __builtin_amdgcn_mfma_f32_16x16x32_bf16(af[i], bf[j], acc[i][j], 0, 0, 0);
    bufr = (bufr == 2) ? 0 : bufr + 1;
    bufw = (bufw == 2) ? 0 : bufw + 1;
  }

#pragma unroll
  for (int i = 0; i < 4; i++) {
    int m0 = bm * 128 + wr * 64 + i * 16 + 4 * h4;
#pragma unroll
    for (int j = 0; j < 4; j++) {
      int n = bn * 128 + wc * 64 + j * 16 + r;
      float bias = (MODE == 3 && e.bias == nullptr) ? 0.f : e.bias[n];
      epi_store<MODE>(e, m0, n, acc[i][j], bias);
    }
  }
}

// -- GEMM v6: 128x256 tile, BK=32, 2-buffer sync pipeline (QKV/fc1) --

template<int MODE>
__global__ __launch_bounds__(256, 2) void k_gemm6(const u16* __restrict__ A, int lda,
                                                  const u16* __restrict__ Bw, int ldb,
                                                  int K, Epi e) {
  __shared__ __align__(16) u16 lds[2][3][4096];  // [buf][A,B-lo,B-hi] = 48 KiB
  int t = threadIdx.x;
  int lane = t & 63, w = t >> 6;
  int h4 = lane >> 4, r = lane & 15;
  int wr = w >> 1, wc = w & 1;          // per-wave 64 rows x 128 cols
  int MBk = gridDim.x, NBk = gridDim.y;
  int nwg = MBk * NBk;
  int orig = blockIdx.y * MBk + blockIdx.x;
  int q8 = nwg >> 3, r8 = nwg & 7, xcd = orig & 7, rk = orig >> 3;
  int wgid = (xcd < r8 ? xcd * (q8 + 1) : r8 * (q8 + 1) + (xcd - r8) * q8) + rk;
  int bm = wgid / NBk, bn = wgid % NBk;

  const u16* Asrc = A + (long)bm * 128 * lda;
  const u16* Bsrc = Bw + (long)bn * 256 * ldb;
  int NT = K >> 5;

  f32x4 acc[4][8];
#pragma unroll
  for (int i = 0; i < 4; i++)
#pragma unroll
    for (int j = 0; j < 8; j++) acc[i][j] = {0.f, 0.f, 0.f, 0.f};

  stage32(lds[0][0], Asrc, lda);
  stage32(lds[0][1], Bsrc, ldb);
  stage32(lds[0][2], Bsrc + (long)128 * ldb, ldb);
  __syncthreads();

  for (int kt = 0; kt < NT; kt++) {
    int cur = kt & 1;
    if (kt + 1 < NT) {
      stage32(lds[cur ^ 1][0], Asrc + (kt + 1) * 32, lda);
      stage32(lds[cur ^ 1][1], Bsrc + (kt + 1) * 32, ldb);
      stage32(lds[cur ^ 1][2], Bsrc + (long)128 * ldb + (kt + 1) * 32, ldb);
    }
    const u16* At = lds[cur][0];
    const u16* Bt = lds[cur][1 + wc];   // wc=0 -> n 0..127, wc=1 -> n 128..255
    s16x8 af[4], bf[8];
#pragma unroll
    for (int i = 0; i < 4; i++) af[i] = frag32(At, wr * 64 + i * 16 + r, h4);
#pragma unroll
    for (int j = 0; j < 8; j++) bf[j] = frag32(Bt, j * 16 + r, h4);
#pragma unroll
    for (int i = 0; i < 4; i++)
#pragma unroll
      for (int j = 0; j < 8; j++)
        acc[i][j] = __builtin_amdgcn_mfma_f32_16x16x32_bf16(af[i], bf[j], acc[i][j], 0, 0, 0);
    __syncthreads();   // drains vmcnt (next-tile stages) + syncs LDS reuse
  }

#pragma unroll
  for (int i = 0; i < 4; i++) {
    int m0 = bm * 128 + wr * 64 + i * 16 + 4 * h4;
#pragma unroll
    for (int j = 0; j < 8; j++) {
      int n = bn * 256 + wc * 128 + j * 16 + r;
      float bias = (MODE == 3 && e.bias == nullptr) ? 0.f : e.bias[n];
      epi_store<MODE>(e, m0, n, acc[i][j], bias);
    }
  }
}

// ---- flash attention v3: LDS-staged KV, MFMA row-sums (ones-trick), cheap defer-max ----

__global__ __launch_bounds__(256, 4) void k_attn2(const u16* __restrict__ qb,
                                                  const u16* __restrict__ kb,
                                                  const u16* __restrict__ vtb,
                                                  u16* __restrict__ aout) {
  __shared__ __align__(16) u16 Kt[2][4096];
  __shared__ __align__(16) u16 Vt[2][4096];
  __shared__ __align__(16) u16 Pl[4][1024];

  int nwg = gridDim.x;                   // 2560
  int orig = blockIdx.x;
  int q8 = nwg >> 3, r8 = nwg & 7, xcd = orig & 7, rk = orig >> 3;
  int wgid = (xcd < r8 ? xcd * (q8 + 1) : r8 * (q8 + 1) + (xcd - r8) * q8) + rk;
  int bh = wgid / NQC, qc = wgid % NQC;  // all q-chunks of a (b,h) contiguous -> same XCD
  int b = bh >> 4, hh = bh & 15;
  int t = threadIdx.x, w = t >> 6, lane = t & 63;
  int h4 = lane >> 4, r = lane & 15;

  const u16* Q  = qb  + (long)bh * SP * 64;
  const u16* Kg = kb  + (long)bh * SP * 64;
  const u16* Vg = vtb + (long)bh * 64 * SP;

  s16x8 ones;
#pragma unroll
  for (int j = 0; j < 8; j++) ones[j] = (short)0x3F80;   // bf16 1.0

  int qt[2];
  bool act[2];
  s16x8 aq0[2], aq1[2];
  f32x4 o[2][4];
  f32x4 ls[2];                            // P row-sums, accumulated by MFMA ones-trick
  float mM[2][4];
#pragma unroll
  for (int sub = 0; sub < 2; sub++) {
    qt[sub] = qc * 8 + w * 2 + sub;
    act[sub] = qt[sub] < SP / 16;
    if (act[sub]) {
      aq0[sub] = *(const s16x8*)&Q[(qt[sub] * 16 + r) * 64 + h4 * 8];
      aq1[sub] = *(const s16x8*)&Q[(qt[sub] * 16 + r) * 64 + 32 + h4 * 8];
    }
    ls[sub] = {0.f, 0.f, 0.f, 0.f};
#pragma unroll
    for (int i = 0; i < 4; i++) { o[sub][i] = {0.f, 0.f, 0.f, 0.f}; mM[sub][i] = -1e30f; }
  }

  // prologue: stage tile 0
  stage64(Kt[0], Kg, 64);
  stage64(Vt[0], Vg, SP);
  VMC(0);
  BAR();

  for (int kt = 0; kt < NKT; kt++) {
    int cur = kt & 1;
    if (kt + 1 < NKT) {                 // issue next-tile loads (other buffer)
      stage64(Kt[cur ^ 1], Kg + (kt + 1) * 64 * 64, 64);
      stage64(Vt[cur ^ 1], Vg + (kt + 1) * 64, SP);
    }
    int kv0 = kt * 64;
    const u16* Kc = Kt[cur];
    const u16* Vc = Vt[cur];
#pragma unroll
    for (int sub = 0; sub < 2; sub++) {
      if (!act[sub]) continue;
      // ---- QK^T: S[q16][kv64]
      f32x4 sf[4];
#pragma unroll
      for (int f = 0; f < 4; f++) {
        sf[f] = {0.f, 0.f, 0.f, 0.f};
        sf[f] = __builtin_amdgcn_mfma_f32_16x16x32_bf16(aq0[sub], frag(Kc, f * 16 + r, 0, h4), sf[f], 0, 0, 0);
        sf[f] = __builtin_amdgcn_mfma_f32_16x16x32_bf16(aq1[sub], frag(Kc, f * 16 + r, 1, h4), sf[f], 0, 0, 0);
      }
      if (kv0 + 64 > S) {               // mask invalid kv columns
#pragma unroll
        for (int f = 0; f < 4; f++)
          if (kv0 + f * 16 + r >= S) {
#pragma unroll
            for (int tt = 0; tt < 4; tt++) sf[f][tt] = -1e30f;
          }
      }
      // ---- defer-max: cheap lane-local test; full reduce only when exceeded
      float mxl[4];
#pragma unroll
      for (int tt = 0; tt < 4; tt++)
        mxl[tt] = fmaxf(fmaxf(sf[0][tt], sf[1][tt]), fmaxf(sf[2][tt], sf[3][tt]));
      int need = 0;
#pragma unroll
      for (int tt = 0; tt < 4; tt++) need |= (mxl[tt] > mM[sub][tt] + 8.f);
      if (__any(need)) {                // rare after first tile
        for (int msk = 1; msk < 16; msk <<= 1) {
#pragma unroll
          for (int tt = 0; tt < 4; tt++) mxl[tt] = fmaxf(mxl[tt], __shfl_xor(mxl[tt], msk));
        }
#pragma unroll
        for (int tt = 0; tt < 4; tt++) {
          float mn = fmaxf(mM[sub][tt], mxl[tt]);
          float sc = ex2(mM[sub][tt] - mn);
          mM[sub][tt] = mn;
          ls[sub][tt] *= sc;
#pragma unroll
          for (int nf = 0; nf < 4; nf++) o[sub][nf][tt] *= sc;
        }
      }
      // ---- P = 2^(s - m)
#pragma unroll
      for (int tt = 0; tt < 4; tt++) {
        float m_ = mM[sub][tt];
        sf[0][tt] = ex2(sf[0][tt] - m_);
        sf[1][tt] = ex2(sf[1][tt] - m_);
        sf[2][tt] = ex2(sf[2][tt] - m_);
        sf[3][tt] = ex2(sf[3][tt] - m_);
      }
      // ---- pack P -> LDS (round-to-nearest bf16), chunk-swizzled rows
      u16* Pw = Pl[w];
#pragma unroll
      for (int f = 0; f < 4; f++)
#pragma unroll
        for (int tt = 0; tt < 4; tt++) {
          int q = 4 * h4 + tt;
          int chunk = (f * 2 + (r >> 3)) ^ (q & 7);
          Pw[q * 64 + chunk * 8 + (r & 7)] = f2bf(sf[f][tt]);
        }
      // ---- PV + row-sum (B = ones: every output column holds sum_k P[q][k])
      s16x8 pa0 = frag(Pw, r, 0, h4);
      s16x8 pa1 = frag(Pw, r, 1, h4);
#pragma unroll
      for (int nf = 0; nf < 4; nf++) {
        o[sub][nf] = __builtin_amdgcn_mfma_f32_16x16x32_bf16(pa0, frag(Vc, nf * 16 + r, 0, h4), o[sub][nf], 0, 0, 0);
        o[sub][nf] = __builtin_amdgcn_mfma_f32_16x16x32_bf16(pa1, frag(Vc, nf * 16 + r, 1, h4), o[sub][nf], 0, 0, 0);
      }
      ls[sub] = __builtin_amdgcn_mfma_f32_16x16x32_bf16(pa0, ones, ls[sub], 0, 0, 0);
      ls[sub] = __builtin_amdgcn_mfma_f32_16x16x32_bf16(pa1, ones, ls[sub], 0, 0, 0);
    }
    VMC(0);
    BAR();
  }

  // ---- write output
#pragma unroll
  for (int sub = 0; sub < 2; sub++) {
    if (!act[sub]) continue;
    float inv[4];
#pragma unroll
    for (int tt = 0; tt < 4; tt++) inv[tt] = 1.f / ls[sub][tt];
#pragma unroll
    for (int nf = 0; nf < 4; nf++)
#pragma unroll
      for (int tt = 0; tt < 4; tt++) {
        int q = qt[sub] * 16 + 4 * h4 + tt;
        if (q < S) aout[((long)b * SP + q) * CC + hh * 64 + nf * 16 + r] = f2bf(o[sub][nf][tt] * inv[tt]);
      }
  }
}

// ---------------- launcher ----------------
// ws liveness map (MiB):
//   0..7      small scratch
//   7..31     weights: wqb 7..13, wob 13..15, wf1b 15..23, wf2b 23..31
//   31..67    qbuf   (QKV gemm -> attn)
//   67..103   kbuf   (QKV gemm -> attn)
//  103..139   vtb    (QKV gemm -> attn); THEN dbuf (outproj -> scatln)
//  139..175   regA:  lnseq (lnseq -> QKV gemm); then aout (attn -> outproj)
//   31..73.5  ln2bf  (scatln -> fc1)  [over dead qbuf+kbuf-head; disjoint from dbuf]
//   74..159   hbuf   (fc1 chunk -> fc2 chunk) [MHALF x 4096 bf16 = 85 MiB]
// peak 175 MiB.

extern "C" void kernel_launch(void* const* d_in, const int* in_sizes, int n_in,
                              void* d_out, int out_size, void* d_ws, size_t ws_size,
                              hipStream_t stream) {
  const float* x    = (const float*)d_in[0];
  const float* lang = (const float*)d_in[1];
  const float* ln1w = (const float*)d_in[2];
  const float* ln1b = (const float*)d_in[3];
  const float* ln2w = (const float*)d_in[4];
  const float* ln2b = (const float*)d_in[5];
  const float* wqkv = (const float*)d_in[6];
  const float* bqkv = (const float*)d_in[7];
  const float* wout = (const float*)d_in[8];
  const float* bout = (const float*)d_in[9];
  const float* wfc1 = (const float*)d_in[10];
  const float* bfc1 = (const float*)d_in[11];
  const float* wfc2 = (const float*)d_in[12];
  const float* bfc2 = (const float*)d_in[13];
  float* out = (float*)d_out;
  char* ws = (char*)d_ws;
  const size_t MiB = 1ull << 20;

  float* lm      = (float*)(ws + 0 * MiB);
  float* score   = (float*)(ws + 1 * MiB);
  float* wall    = (float*)(ws + 2 * MiB);
  int*   rowmap  = (int*)  (ws + 3 * MiB);
  int*   selsrc  = (int*)  (ws + 4 * MiB);
  int*   lowlist = (int*)  (ws + 5 * MiB);
  float* lowtok  = (float*)(ws + 6 * MiB);
  u16* wqb  = (u16*)(ws + 7 * MiB);
  u16* wob  = (u16*)(ws + 13 * MiB);
  u16* wf1b = (u16*)(ws + 15 * MiB);
  u16* wf2b = (u16*)(ws + 23 * MiB);
  u16* qbuf = (u16*)(ws + 31 * MiB);
  u16* kbuf = (u16*)(ws + 67 * MiB);
  u16* vtb  = (u16*)(ws + 103 * MiB);
  u16* regA = (u16*)(ws + 139 * MiB);   // lnseq -> aout (36 MiB each, M1P rows)
  u16* lnseq = regA;
  u16* aout  = regA;
  u16* dbuf  = vtb;                     // outproj output; vtb dead after attn
  u16* ln2bf = qbuf;                    // 42.5 MiB (31..73.5); disjoint from dbuf
  u16* hbuf  = (u16*)(ws + 74 * MiB);   // 85 MiB (74..159); disjoint from ln2bf

  // weight conversion fp32 -> bf16
  {
    int n4;
    n4 = 3072 * 1024 / 4; k_f2bf4<<<(n4 + 255) / 256, 256, 0, stream>>>(wqkv, wqb, n4);
    n4 = 1024 * 1024 / 4; k_f2bf4<<<(n4 + 255) / 256, 256, 0, stream>>>(wout, wob, n4);
    n4 = 4096 * 1024 / 4; k_f2bf4<<<(n4 + 255) / 256, 256, 0, stream>>>(wfc1, wf1b, n4);
    n4 = 1024 * 4096 / 4; k_f2bf4<<<(n4 + 255) / 256, 256, 0, stream>>>(wfc2, wf2b, n4);
  }

  k_langmean<<<BB, 256, 0, stream>>>(lang, lm);
  k_score<<<NPATCH * BB, 256, 0, stream>>>(x, lm, score);
  k_select<<<BB, 1024, 0, stream>>>(score, wall, rowmap, selsrc, lowlist);
  k_lowtok<<<dim3(BB, 4), 256, 0, stream>>>(x, wall, lowlist, lowtok);
  k_lnseq<<<dim3(SP, BB), 256, 0, stream>>>(x, lowtok, selsrc, ln1w, ln1b, lnseq);

  {
    Epi e = {};
    e.bias = bqkv; e.qb = qbuf; e.kb = kbuf; e.vtb = vtb; e.mvalid = M1P;
    k_gemm6<0><<<dim3(M1P / 128, 3072 / 256), 256, 0, stream>>>(lnseq, 1024, wqb, 1024, 1024, e);
  }

  k_attn2<<<BB * 16 * NQC, 256, 0, stream>>>(qbuf, kbuf, vtb, aout);

  {
    Epi e = {};
    e.bias = bout; e.obf = dbuf; e.mvalid = M1P; e.ldc = 1024;
    k_gemm5<1><<<dim3(M1P / 128, 1024 / 128), 256, 0, stream>>>(aout, 1024, wob, 1024, 1024, e);
  }

  k_scatln<<<M2P, 256, 0, stream>>>(x, dbuf, rowmap, ln2w, ln2b, out, ln2bf);

  // MLP: M-split into two row-halves; per half, fc1 over full hidden (N=4096,
  // ldc=4096 into hbuf) then fc2 as a single K=4096 pass -> ONE fp32 RMW of out.
  for (int mc = 0; mc < 2; mc++) {
    int rvalid = (mc == 0) ? MHALF : (M2 - MHALF);   // 10880, 10784
    Epi e2 = {};
    e2.bias = bfc1; e2.obf = hbuf; e2.mvalid = MHALF; e2.ldc = 4096;
    k_gemm6<2><<<dim3(MHALF / 128, 4096 / 256), 256, 0, stream>>>(
        ln2bf + (long)mc * MHALF * 1024, 1024, wf1b, 1024, 1024, e2);
    Epi e3 = {};
    e3.bias = bfc2; e3.of = out + (long)mc * MHALF * CC; e3.mvalid = rvalid;
    k_gemm5<3><<<dim3(MHALF / 128, 1024 / 128), 256, 0, stream>>>(
        hbuf, 4096, wf2b, 4096, 4096, e3);
  }
}

// Round 13
// 1013.571 us; speedup vs baseline: 1.0875x; 1.0105x over previous
//
#include <hip/hip_runtime.h>
#include <hip/hip_bf16.h>

typedef unsigned short u16;
typedef __attribute__((ext_vector_type(4))) float f32x4;
typedef __attribute__((ext_vector_type(8))) short s16x8;

#define DEVI __device__ __forceinline__

static constexpr int NPATCH = 676;
static constexpr int KSEL   = 540;   // int(676*0.8)
static constexpr int NLOW   = 136;
static constexpr int BB     = 32;
static constexpr int CC     = 1024;
static constexpr int S      = 542;   // 1 + 540 + 1
static constexpr int SP     = 576;   // padded seq (9*64)
static constexpr int M1P    = SP * BB;     // 18432 rows, seq-major: m = b*SP + s
static constexpr int NTOK   = 677;
static constexpr int M2     = NTOK * BB;   // 21664
static constexpr int M2P    = 21760;       // pad to 128/256
static constexpr int MHALF  = 10880;       // M2P/2 (85*128)
static constexpr int NKT    = SP / 64;     // 9 kv tiles
static constexpr int NQC    = 5;           // q-chunks of 8 qtiles (36 qtiles total)

DEVI u16 f2bf(float f) {
  unsigned u = __float_as_uint(f);
  u += 0x7fffu + ((u >> 16) & 1u);
  return (u16)(u >> 16);
}
// HW RTNE cast (compiler pairs into v_cvt_pk_bf16_f32); bit-identical to f2bf
DEVI u16 f2bf_fast(float f) {
  __hip_bfloat16 h = __float2bfloat16(f);
  return *(u16*)&h;
}
DEVI float bf2f(u16 h) { return __uint_as_float(((unsigned)h) << 16); }
DEVI float ex2(float x) { float r; asm("v_exp_f32 %0, %1" : "=v"(r) : "v"(x)); return r; }

DEVI void gld16(const void* g, void* l) {
  __builtin_amdgcn_global_load_lds((const __attribute__((address_space(1))) void*)g,
                                   (__attribute__((address_space(3))) void*)l,
                                   16, 0, 0);
}

DEVI void BAR() {
  asm volatile("" ::: "memory");
  __builtin_amdgcn_s_barrier();
  asm volatile("" ::: "memory");
}
#define VMC(N) asm volatile("s_waitcnt vmcnt(" #N ")" ::: "memory")

// ---------------- small kernels ----------------

// merged weight conversion: 4 fp32 sources -> contiguous bf16 region
__global__ void k_wconv(const float* __restrict__ s0, const float* __restrict__ s1,
                        const float* __restrict__ s2, const float* __restrict__ s3,
                        u16* __restrict__ out) {
  int i = blockIdx.x * blockDim.x + threadIdx.x;   // float4 index, total 3145728
  const float* src;
  long off;
  if (i < 786432)       { src = s0; off = 0; }
  else if (i < 1048576) { src = s1; off = 786432; }
  else if (i < 2097152) { src = s2; off = 1048576; }
  else                  { src = s3; off = 2097152; }
  float4 v = ((const float4*)src)[i - off];
  unsigned long long p = (unsigned long long)f2bf(v.x)
                       | ((unsigned long long)f2bf(v.y) << 16)
                       | ((unsigned long long)f2bf(v.z) << 32)
                       | ((unsigned long long)f2bf(v.w) << 48);
  *(unsigned long long*)&out[(long)i * 4] = p;
}

__global__ void k_langmean(const float* __restrict__ lang, float* __restrict__ lm) {
  int b = blockIdx.x, t = threadIdx.x;
  float a0 = 0, a1 = 0, a2 = 0, a3 = 0;
  for (int l = 0; l < 77; l++) {
    float4 v = ((const float4*)(lang + ((long)l * BB + b) * CC))[t];
    a0 += v.x; a1 += v.y; a2 += v.z; a3 += v.w;
  }
  const float inv = 1.f / 77.f;
  float4 o; o.x = a0 * inv; o.y = a1 * inv; o.z = a2 * inv; o.w = a3 * inv;
  ((float4*)(lm + b * CC))[t] = o;
}

__global__ void k_score(const float* __restrict__ x, const float* __restrict__ lm,
                        float* __restrict__ score) {
  int nb = blockIdx.x;
  int n = nb >> 5, b = nb & 31;
  int t = threadIdx.x;
  float4 xv = ((const float4*)(x + ((long)(n + 1) * BB + b) * CC))[t];
  float4 lv = ((const float4*)(lm + b * CC))[t];
  float s = xv.x * lv.x + xv.y * lv.y + xv.z * lv.z + xv.w * lv.w;
  for (int m = 1; m < 64; m <<= 1) s += __shfl_xor(s, m);
  __shared__ float sm[4];
  if ((t & 63) == 0) sm[t >> 6] = s;
  __syncthreads();
  if (t == 0) score[n * BB + b] = sm[0] + sm[1] + sm[2] + sm[3];
}

__global__ void k_select(const float* __restrict__ score, float* __restrict__ wall,
                         int* __restrict__ rowmap, int* __restrict__ selsrc,
                         int* __restrict__ lowlist) {
  int b = blockIdx.x, t = threadIdx.x;
  __shared__ float sc[NPATCH];
  __shared__ int hf[NPATCH];
  __shared__ float red[2];
  if (t < NPATCH) sc[t] = score[t * BB + b];
  __syncthreads();
  int high = 0;
  if (t < NPATCH) {
    float s = sc[t];
    int r = 0;
    for (int m = 0; m < NPATCH; m++) {
      float sm_ = sc[m];
      r += (sm_ > s) || (sm_ == s && m < t);
    }
    high = (r < KSEL);
    hf[t] = high;
  }
  __syncthreads();
  if (t < NPATCH) {
    int p = 0;
    for (int m = 0; m < t; m++) p += hf[m];
    if (high) {
      rowmap[b * NPATCH + t] = 1 + p;
      selsrc[b * S + 1 + p] = t + 1;        // row index into full x
    } else {
      rowmap[b * NPATCH + t] = S - 1;
      lowlist[b * NLOW + (t - p)] = t;
    }
  }
  if (t == 0) selsrc[b * S + 0] = 0;
  __syncthreads();
  if (t == 0) {
    float m = -3e38f;
    for (int i = 0; i < NPATCH; i++) if (!hf[i]) m = fmaxf(m, sc[i]);
    float d = 0;
    for (int i = 0; i < NPATCH; i++) if (!hf[i]) d += __expf(sc[i] - m);
    red[0] = m; red[1] = d;
  }
  __syncthreads();
  if (t < NPATCH) wall[b * NPATCH + t] = hf[t] ? 0.f : __expf(sc[t] - red[0]) / red[1];
}

__global__ void k_lowtok(const float* __restrict__ x, const float* __restrict__ wall,
                         const int* __restrict__ lowlist, float* __restrict__ lowtok) {
  int b = blockIdx.x, ch = blockIdx.y;
  int c = ch * 256 + threadIdx.x;
  float acc = 0.f;
  for (int i = 0; i < NLOW; i++) {
    int n = lowlist[b * NLOW + i];
    acc += wall[b * NPATCH + n] * x[((long)(n + 1) * BB + b) * CC + c];
  }
  lowtok[b * CC + c] = acc;
}

// gather + LayerNorm -> bf16 seq rows, SEQ-MAJOR: row = b*SP + s (pad rows zeroed)
__global__ void k_lnseq(const float* __restrict__ x, const float* __restrict__ lowtok,
                        const int* __restrict__ selsrc, const float* __restrict__ w,
                        const float* __restrict__ bias, u16* __restrict__ out) {
  int s = blockIdx.x, b = blockIdx.y, t = threadIdx.x;
  u16* orow = out + ((long)b * SP + s) * CC;
  if (s >= S) { *(unsigned long long*)&orow[4 * t] = 0ULL; return; }
  const float* src;
  if (s == 0)          src = x + (long)b * CC;
  else if (s == S - 1) src = lowtok + (long)b * CC;
  else                 src = x + ((long)selsrc[b * S + s] * BB + b) * CC;
  float4 v = ((const float4*)src)[t];
  float ss = v.x + v.y + v.z + v.w;
  float s2 = v.x * v.x + v.y * v.y + v.z * v.z + v.w * v.w;
  for (int k = 1; k < 64; k <<= 1) { ss += __shfl_xor(ss, k); s2 += __shfl_xor(s2, k); }
  __shared__ float sa[4], sb[4];
  if ((t & 63) == 0) { sa[t >> 6] = ss; sb[t >> 6] = s2; }
  __syncthreads();
  ss = sa[0] + sa[1] + sa[2] + sa[3];
  s2 = sb[0] + sb[1] + sb[2] + sb[3];
  float mu = ss * (1.f / CC);
  float var = s2 * (1.f / CC) - mu * mu;
  float rs = rsqrtf(var + 1e-5f);
  int c = 4 * t;
  unsigned long long p = (unsigned long long)f2bf((v.x - mu) * rs * w[c]     + bias[c])
                       | ((unsigned long long)f2bf((v.y - mu) * rs * w[c + 1] + bias[c + 1]) << 16)
                       | ((unsigned long long)f2bf((v.z - mu) * rs * w[c + 2] + bias[c + 2]) << 32)
                       | ((unsigned long long)f2bf((v.w - mu) * rs * w[c + 3] + bias[c + 3]) << 48);
  *(unsigned long long*)&orow[4 * t] = p;
}

// fused scatter (x + gathered d -> out fp32) + LayerNorm(out) -> bf16
__global__ void k_scatln(const float* __restrict__ x, const u16* __restrict__ dbuf,
                         const int* __restrict__ rowmap, const float* __restrict__ w,
                         const float* __restrict__ bias, float* __restrict__ out,
                         u16* __restrict__ lnout) {
  int m = blockIdx.x, t = threadIdx.x;
  u16* orow = lnout + (long)m * CC;
  if (m >= M2) { *(unsigned long long*)&orow[4 * t] = 0ULL; return; }
  int nf = m >> 5, b = m & 31;
  int srow = (nf == 0) ? 0 : rowmap[b * NPATCH + (nf - 1)];
  float4 xv = ((const float4*)(x + (long)m * CC))[t];
  unsigned long long dp = *(const unsigned long long*)&dbuf[((long)b * SP + srow) * CC + 4 * t];
  float4 v;
  v.x = xv.x + bf2f((u16)(dp));
  v.y = xv.y + bf2f((u16)(dp >> 16));
  v.z = xv.z + bf2f((u16)(dp >> 32));
  v.w = xv.w + bf2f((u16)(dp >> 48));
  ((float4*)(out + (long)m * CC))[t] = v;
  float ss = v.x + v.y + v.z + v.w;
  float s2 = v.x * v.x + v.y * v.y + v.z * v.z + v.w * v.w;
  for (int k = 1; k < 64; k <<= 1) { ss += __shfl_xor(ss, k); s2 += __shfl_xor(s2, k); }
  __shared__ float sa[4], sb[4];
  if ((t & 63) == 0) { sa[t >> 6] = ss; sb[t >> 6] = s2; }
  __syncthreads();
  ss = sa[0] + sa[1] + sa[2] + sa[3];
  s2 = sb[0] + sb[1] + sb[2] + sb[3];
  float mu = ss * (1.f / CC);
  float var = s2 * (1.f / CC) - mu * mu;
  float rs = rsqrtf(var + 1e-5f);
  int c = 4 * t;
  unsigned long long p = (unsigned long long)f2bf((v.x - mu) * rs * w[c]     + bias[c])
                       | ((unsigned long long)f2bf((v.y - mu) * rs * w[c + 1] + bias[c + 1]) << 16)
                       | ((unsigned long long)f2bf((v.z - mu) * rs * w[c + 2] + bias[c + 2]) << 32)
                       | ((unsigned long long)f2bf((v.w - mu) * rs * w[c + 3] + bias[c + 3]) << 48);
  *(unsigned long long*)&orow[4 * t] = p;
}

// ---------------- GEMM common ----------------

struct Epi {
  const float* bias;
  u16* obf;
  float* of;
  u16 *qb, *kb, *vtb;
  int mvalid, ldc;
};

// 128x32 K-step tile packed as 64 LDS-rows x 64 cols (8 KiB).
DEVI void stage32(u16* dst, const u16* src, int ld) {
  int t = threadIdx.x;
#pragma unroll
  for (int q = 0; q < 2; q++) {
    int s = t + q * 256;
    int R = s >> 3, clp = s & 7;
    int lc = clp ^ (R & 7);
    int m = 2 * R + (lc >> 2), kc = lc & 3;
    gld16(src + (long)m * ld + kc * 8, dst + s * 8);
  }
}

DEVI s16x8 frag32(const u16* tile, int m, int h4) {
  int R = m >> 1;
  int phys = ((((m & 1) << 2) | h4) ^ (R & 7));
  return *(const s16x8*)(tile + R * 64 + phys * 8);
}

// attn helpers (64-row x 64-col tiles, verified swizzle pair)
DEVI void stage64(u16* dst, const u16* src, int ld) {
  int t = threadIdx.x;
  int c = t & 7, r0 = t >> 3;             // rows 0..31
  gld16(src + (long)r0 * ld + ((c ^ (r0 & 7)) << 3), dst + t * 8);
  int r1 = r0 + 32;
  gld16(src + (long)r1 * ld + ((c ^ (r1 & 7)) << 3), dst + 2048 + t * 8);
}

DEVI s16x8 frag(const u16* half, int rh, int kk, int h4) {
  int chunk = ((kk << 2) | h4) ^ (rh & 7);
  return *(const s16x8*)(half + rh * 64 + chunk * 8);
}

// shared epilogue element-writer
template<int MODE>
DEVI void epi_store(const Epi& e, int m0, int n, const f32x4& a, float bias) {
  const float QSC = 0.125f * 1.44269504088896f;
  if (MODE == 0) {
    int part = n >> 10, cc = n & 1023;
    int hh = cc >> 6, dd = cc & 63;
    int b0 = m0 / SP, s0 = m0 % SP;
    if (part == 2) {
      u16 pk[4];
#pragma unroll
      for (int tt = 0; tt < 4; tt++) pk[tt] = f2bf(a[tt] + bias);
      *(unsigned long long*)&e.vtb[((long)(b0 * 16 + hh) * 64 + dd) * SP + s0] =
          *(unsigned long long*)pk;
    } else {
      u16* dst = (part == 0 ? e.qb : e.kb) + ((long)(b0 * 16 + hh) * SP + s0) * 64 + dd;
      float scl = (part == 0) ? QSC : 1.f;
#pragma unroll
      for (int tt = 0; tt < 4; tt++) dst[tt * 64] = f2bf((a[tt] + bias) * scl);
    }
  } else if (MODE == 1) {
#pragma unroll
    for (int tt = 0; tt < 4; tt++)
      e.obf[(long)(m0 + tt) * e.ldc + n] = f2bf(a[tt] + bias);
  } else if (MODE == 2) {
#pragma unroll
    for (int tt = 0; tt < 4; tt++) {
      float v = a[tt] + bias;
      v = v / (1.f + __expf(-1.702f * v));
      e.obf[(long)(m0 + tt) * e.ldc + n] = f2bf(v);
    }
  } else {
#pragma unroll
    for (int tt = 0; tt < 4; tt++) {
      int m = m0 + tt;
      if (m < e.mvalid) e.of[(long)m * CC + n] += a[tt] + bias;
    }
  }
}

// -- GEMM v5: 128x128 tile, BK=32, 3-buffer rotation, counted vmcnt (outproj/fc2) --

template<int MODE>
__global__ __launch_bounds__(256, 3) void k_gemm5(const u16* __restrict__ A, int lda,
                                                  const u16* __restrict__ Bw, int ldb,
                                                  int K, Epi e) {
  __shared__ __align__(16) u16 lds[3][2][4096];  // 48 KiB -> 3 blk/CU
  int t = threadIdx.x;
  int lane = t & 63, w = t >> 6;
  int h4 = lane >> 4, r = lane & 15;
  int wr = w >> 1, wc = w & 1;
  int MBk = gridDim.x, NBk = gridDim.y;
  int nwg = MBk * NBk;
  int orig = blockIdx.y * MBk + blockIdx.x;
  int q8 = nwg >> 3, r8 = nwg & 7, xcd = orig & 7, rk = orig >> 3;
  int wgid = (xcd < r8 ? xcd * (q8 + 1) : r8 * (q8 + 1) + (xcd - r8) * q8) + rk;
  int bm = wgid / NBk, bn = wgid % NBk;

  const u16* Asrc = A + (long)bm * 128 * lda;
  const u16* Bsrc = Bw + (long)bn * 128 * ldb;
  int NT = K >> 5;

  f32x4 acc[4][4];
#pragma unroll
  for (int i = 0; i < 4; i++)
#pragma unroll
    for (int j = 0; j < 4; j++) acc[i][j] = {0.f, 0.f, 0.f, 0.f};

  stage32(lds[0][0], Asrc, lda);
  stage32(lds[0][1], Bsrc, ldb);
  if (NT > 1) {
    stage32(lds[1][0], Asrc + 32, lda);
    stage32(lds[1][1], Bsrc + 32, ldb);
  }

  int bufr = 0, bufw = 2;
  for (int kt = 0; kt < NT; kt++) {
    if (kt + 1 < NT) { VMC(4); } else { VMC(0); }
    BAR();
    if (kt + 2 < NT) {
      stage32(lds[bufw][0], Asrc + (kt + 2) * 32, lda);
      stage32(lds[bufw][1], Bsrc + (kt + 2) * 32, ldb);
    }
    const u16* At = lds[bufr][0];
    const u16* Bt = lds[bufr][1];
    s16x8 af[4], bf[4];
#pragma unroll
    for (int i = 0; i < 4; i++) af[i] = frag32(At, wr * 64 + i * 16 + r, h4);
#pragma unroll
    for (int j = 0; j < 4; j++) bf[j] = frag32(Bt, wc * 64 + j * 16 + r, h4);
#pragma unroll
    for (int i = 0; i < 4; i++)
#pragma unroll
      for (int j = 0; j < 4; j++)
        acc[i][j] = __builtin_amdgcn_mfma_f32_16x16x32_bf16(af[i], bf[j], acc[i][j], 0, 0, 0);
    bufr = (bufr == 2) ? 0 : bufr + 1;
    bufw = (bufw == 2) ? 0 : bufw + 1;
  }

#pragma unroll
  for (int i = 0; i < 4; i++) {
    int m0 = bm * 128 + wr * 64 + i * 16 + 4 * h4;
#pragma unroll
    for (int j = 0; j < 4; j++) {
      int n = bn * 128 + wc * 64 + j * 16 + r;
      float bias = (MODE == 3 && e.bias == nullptr) ? 0.f : e.bias[n];
      epi_store<MODE>(e, m0, n, acc[i][j], bias);
    }
  }
}

// -- GEMM v6: 128x256 tile, BK=32, 2-buffer sync pipeline (QKV/fc1) --

template<int MODE>
__global__ __launch_bounds__(256, 2) void k_gemm6(const u16* __restrict__ A, int lda,
                                                  const u16* __restrict__ Bw, int ldb,
                                                  int K, Epi e) {
  __shared__ __align__(16) u16 lds[2][3][4096];  // [buf][A,B-lo,B-hi] = 48 KiB
  int t = threadIdx.x;
  int lane = t & 63, w = t >> 6;
  int h4 = lane >> 4, r = lane & 15;
  int wr = w >> 1, wc = w & 1;          // per-wave 64 rows x 128 cols
  int MBk = gridDim.x, NBk = gridDim.y;
  int nwg = MBk * NBk;
  int orig = blockIdx.y * MBk + blockIdx.x;
  int q8 = nwg >> 3, r8 = nwg & 7, xcd = orig & 7, rk = orig >> 3;
  int wgid = (xcd < r8 ? xcd * (q8 + 1) : r8 * (q8 + 1) + (xcd - r8) * q8) + rk;
  int bm = wgid / NBk, bn = wgid % NBk;

  const u16* Asrc = A + (long)bm * 128 * lda;
  const u16* Bsrc = Bw + (long)bn * 256 * ldb;
  int NT = K >> 5;

  f32x4 acc[4][8];
#pragma unroll
  for (int i = 0; i < 4; i++)
#pragma unroll
    for (int j = 0; j < 8; j++) acc[i][j] = {0.f, 0.f, 0.f, 0.f};

  stage32(lds[0][0], Asrc, lda);
  stage32(lds[0][1], Bsrc, ldb);
  stage32(lds[0][2], Bsrc + (long)128 * ldb, ldb);
  __syncthreads();

  for (int kt = 0; kt < NT; kt++) {
    int cur = kt & 1;
    if (kt + 1 < NT) {
      stage32(lds[cur ^ 1][0], Asrc + (kt + 1) * 32, lda);
      stage32(lds[cur ^ 1][1], Bsrc + (kt + 1) * 32, ldb);
      stage32(lds[cur ^ 1][2], Bsrc + (long)128 * ldb + (kt + 1) * 32, ldb);
    }
    const u16* At = lds[cur][0];
    const u16* Bt = lds[cur][1 + wc];   // wc=0 -> n 0..127, wc=1 -> n 128..255
    s16x8 af[4], bf[8];
#pragma unroll
    for (int i = 0; i < 4; i++) af[i] = frag32(At, wr * 64 + i * 16 + r, h4);
#pragma unroll
    for (int j = 0; j < 8; j++) bf[j] = frag32(Bt, j * 16 + r, h4);
#pragma unroll
    for (int i = 0; i < 4; i++)
#pragma unroll
      for (int j = 0; j < 8; j++)
        acc[i][j] = __builtin_amdgcn_mfma_f32_16x16x32_bf16(af[i], bf[j], acc[i][j], 0, 0, 0);
    __syncthreads();   // drains vmcnt (next-tile stages) + syncs LDS reuse
  }

#pragma unroll
  for (int i = 0; i < 4; i++) {
    int m0 = bm * 128 + wr * 64 + i * 16 + 4 * h4;
#pragma unroll
    for (int j = 0; j < 8; j++) {
      int n = bn * 256 + wc * 128 + j * 16 + r;
      float bias = (MODE == 3 && e.bias == nullptr) ? 0.f : e.bias[n];
      epi_store<MODE>(e, m0, n, acc[i][j], bias);
    }
  }
}

// ---- flash attention v3: LDS-staged KV, MFMA row-sums (ones-trick), cheap defer-max ----

__global__ __launch_bounds__(256, 4) void k_attn2(const u16* __restrict__ qb,
                                                  const u16* __restrict__ kb,
                                                  const u16* __restrict__ vtb,
                                                  u16* __restrict__ aout) {
  __shared__ __align__(16) u16 Kt[2][4096];
  __shared__ __align__(16) u16 Vt[2][4096];
  __shared__ __align__(16) u16 Pl[4][1024];

  int nwg = gridDim.x;                   // 2560
  int orig = blockIdx.x;
  int q8 = nwg >> 3, r8 = nwg & 7, xcd = orig & 7, rk = orig >> 3;
  int wgid = (xcd < r8 ? xcd * (q8 + 1) : r8 * (q8 + 1) + (xcd - r8) * q8) + rk;
  int bh = wgid / NQC, qc = wgid % NQC;  // all q-chunks of a (b,h) contiguous -> same XCD
  int b = bh >> 4, hh = bh & 15;
  int t = threadIdx.x, w = t >> 6, lane = t & 63;
  int h4 = lane >> 4, r = lane & 15;

  const u16* Q  = qb  + (long)bh * SP * 64;
  const u16* Kg = kb  + (long)bh * SP * 64;
  const u16* Vg = vtb + (long)bh * 64 * SP;

  s16x8 ones;
#pragma unroll
  for (int j = 0; j < 8; j++) ones[j] = (short)0x3F80;   // bf16 1.0

  int qt[2];
  bool act[2];
  s16x8 aq0[2], aq1[2];
  f32x4 o[2][4];
  f32x4 ls[2];                            // P row-sums, accumulated by MFMA ones-trick
  float mM[2][4];
#pragma unroll
  for (int sub = 0; sub < 2; sub++) {
    qt[sub] = qc * 8 + w * 2 + sub;
    act[sub] = qt[sub] < SP / 16;
    if (act[sub]) {
      aq0[sub] = *(const s16x8*)&Q[(qt[sub] * 16 + r) * 64 + h4 * 8];
      aq1[sub] = *(const s16x8*)&Q[(qt[sub] * 16 + r) * 64 + 32 + h4 * 8];
    }
    ls[sub] = {0.f, 0.f, 0.f, 0.f};
#pragma unroll
    for (int i = 0; i < 4; i++) { o[sub][i] = {0.f, 0.f, 0.f, 0.f}; mM[sub][i] = -1e30f; }
  }

  // prologue: stage tile 0
  stage64(Kt[0], Kg, 64);
  stage64(Vt[0], Vg, SP);
  VMC(0);
  BAR();

  for (int kt = 0; kt < NKT; kt++) {
    int cur = kt & 1;
    if (kt + 1 < NKT) {                 // issue next-tile loads (other buffer)
      stage64(Kt[cur ^ 1], Kg + (kt + 1) * 64 * 64, 64);
      stage64(Vt[cur ^ 1], Vg + (kt + 1) * 64, SP);
    }
    int kv0 = kt * 64;
    const u16* Kc = Kt[cur];
    const u16* Vc = Vt[cur];
#pragma unroll
    for (int sub = 0; sub < 2; sub++) {
      if (!act[sub]) continue;
      // ---- QK^T: S[q16][kv64]
      f32x4 sf[4];
#pragma unroll
      for (int f = 0; f < 4; f++) {
        sf[f] = {0.f, 0.f, 0.f, 0.f};
        sf[f] = __builtin_amdgcn_mfma_f32_16x16x32_bf16(aq0[sub], frag(Kc, f * 16 + r, 0, h4), sf[f], 0, 0, 0);
        sf[f] = __builtin_amdgcn_mfma_f32_16x16x32_bf16(aq1[sub], frag(Kc, f * 16 + r, 1, h4), sf[f], 0, 0, 0);
      }
      if (kv0 + 64 > S) {               // mask invalid kv columns
#pragma unroll
        for (int f = 0; f < 4; f++)
          if (kv0 + f * 16 + r >= S) {
#pragma unroll
            for (int tt = 0; tt < 4; tt++) sf[f][tt] = -1e30f;
          }
      }
      // ---- defer-max: cheap lane-local test; full reduce only when exceeded
      float mxl[4];
#pragma unroll
      for (int tt = 0; tt < 4; tt++)
        mxl[tt] = fmaxf(fmaxf(sf[0][tt], sf[1][tt]), fmaxf(sf[2][tt], sf[3][tt]));
      int need = 0;
#pragma unroll
      for (int tt = 0; tt < 4; tt++) need |= (mxl[tt] > mM[sub][tt] + 8.f);
      if (__any(need)) {                // rare after first tile
        for (int msk = 1; msk < 16; msk <<= 1) {
#pragma unroll
          for (int tt = 0; tt < 4; tt++) mxl[tt] = fmaxf(mxl[tt], __shfl_xor(mxl[tt], msk));
        }
#pragma unroll
        for (int tt = 0; tt < 4; tt++) {
          float mn = fmaxf(mM[sub][tt], mxl[tt]);
          float sc = ex2(mM[sub][tt] - mn);
          mM[sub][tt] = mn;
          ls[sub][tt] *= sc;
#pragma unroll
          for (int nf = 0; nf < 4; nf++) o[sub][nf][tt] *= sc;
        }
      }
      // ---- P = 2^(s - m)
#pragma unroll
      for (int tt = 0; tt < 4; tt++) {
        float m_ = mM[sub][tt];
        sf[0][tt] = ex2(sf[0][tt] - m_);
        sf[1][tt] = ex2(sf[1][tt] - m_);
        sf[2][tt] = ex2(sf[2][tt] - m_);
        sf[3][tt] = ex2(sf[3][tt] - m_);
      }
      // ---- pack P -> LDS (HW RTNE cvt, compiler pairs to v_cvt_pk_bf16_f32)
      u16* Pw = Pl[w];
#pragma unroll
      for (int f = 0; f < 4; f++)
#pragma unroll
        for (int tt = 0; tt < 4; tt++) {
          int q = 4 * h4 + tt;
          int chunk = (f * 2 + (r >> 3)) ^ (q & 7);
          Pw[q * 64 + chunk * 8 + (r & 7)] = f2bf_fast(sf[f][tt]);
        }
      // ---- PV + row-sum (B = ones: every output column holds sum_k P[q][k])
      s16x8 pa0 = frag(Pw, r, 0, h4);
      s16x8 pa1 = frag(Pw, r, 1, h4);
#pragma unroll
      for (int nf = 0; nf < 4; nf++) {
        o[sub][nf] = __builtin_amdgcn_mfma_f32_16x16x32_bf16(pa0, frag(Vc, nf * 16 + r, 0, h4), o[sub][nf], 0, 0, 0);
        o[sub][nf] = __builtin_amdgcn_mfma_f32_16x16x32_bf16(pa1, frag(Vc, nf * 16 + r, 1, h4), o[sub][nf], 0, 0, 0);
      }
      ls[sub] = __builtin_amdgcn_mfma_f32_16x16x32_bf16(pa0, ones, ls[sub], 0, 0, 0);
      ls[sub] = __builtin_amdgcn_mfma_f32_16x16x32_bf16(pa1, ones, ls[sub], 0, 0, 0);
    }
    VMC(0);
    BAR();
  }

  // ---- write output
#pragma unroll
  for (int sub = 0; sub < 2; sub++) {
    if (!act[sub]) continue;
    float inv[4];
#pragma unroll
    for (int tt = 0; tt < 4; tt++) inv[tt] = 1.f / ls[sub][tt];
#pragma unroll
    for (int nf = 0; nf < 4; nf++)
#pragma unroll
      for (int tt = 0; tt < 4; tt++) {
        int q = qt[sub] * 16 + 4 * h4 + tt;
        if (q < S) aout[((long)b * SP + q) * CC + hh * 64 + nf * 16 + r] = f2bf_fast(o[sub][nf][tt] * inv[tt]);
      }
  }
}

// ---------------- launcher ----------------
// ws liveness map (MiB):
//   0..7      small scratch
//   7..31     weights (contiguous bf16): wqb 7..13, wob 13..15, wf1b 15..23, wf2b 23..31
//   31..67    qbuf   (QKV gemm -> attn)
//   67..103   kbuf   (QKV gemm -> attn)
//  103..139   vtb    (QKV gemm -> attn); THEN dbuf (outproj -> scatln)
//  139..175   regA:  lnseq (lnseq -> QKV gemm); then aout (attn -> outproj)
//   31..73.5  ln2bf  (scatln -> fc1)  [over dead qbuf+kbuf-head; disjoint from dbuf]
//   74..159   hbuf   (fc1 chunk -> fc2 chunk) [MHALF x 4096 bf16 = 85 MiB]
// peak 175 MiB.

extern "C" void kernel_launch(void* const* d_in, const int* in_sizes, int n_in,
                              void* d_out, int out_size, void* d_ws, size_t ws_size,
                              hipStream_t stream) {
  const float* x    = (const float*)d_in[0];
  const float* lang = (const float*)d_in[1];
  const float* ln1w = (const float*)d_in[2];
  const float* ln1b = (const float*)d_in[3];
  const float* ln2w = (const float*)d_in[4];
  const float* ln2b = (const float*)d_in[5];
  const float* wqkv = (const float*)d_in[6];
  const float* bqkv = (const float*)d_in[7];
  const float* wout = (const float*)d_in[8];
  const float* bout = (const float*)d_in[9];
  const float* wfc1 = (const float*)d_in[10];
  const float* bfc1 = (const float*)d_in[11];
  const float* wfc2 = (const float*)d_in[12];
  const float* bfc2 = (const float*)d_in[13];
  float* out = (float*)d_out;
  char* ws = (char*)d_ws;
  const size_t MiB = 1ull << 20;

  float* lm      = (float*)(ws + 0 * MiB);
  float* score   = (float*)(ws + 1 * MiB);
  float* wall    = (float*)(ws + 2 * MiB);
  int*   rowmap  = (int*)  (ws + 3 * MiB);
  int*   selsrc  = (int*)  (ws + 4 * MiB);
  int*   lowlist = (int*)  (ws + 5 * MiB);
  float* lowtok  = (float*)(ws + 6 * MiB);
  u16* wqb  = (u16*)(ws + 7 * MiB);
  u16* wob  = (u16*)(ws + 13 * MiB);
  u16* wf1b = (u16*)(ws + 15 * MiB);
  u16* wf2b = (u16*)(ws + 23 * MiB);
  u16* qbuf = (u16*)(ws + 31 * MiB);
  u16* kbuf = (u16*)(ws + 67 * MiB);
  u16* vtb  = (u16*)(ws + 103 * MiB);
  u16* regA = (u16*)(ws + 139 * MiB);   // lnseq -> aout (36 MiB each, M1P rows)
  u16* lnseq = regA;
  u16* aout  = regA;
  u16* dbuf  = vtb;                     // outproj output; vtb dead after attn
  u16* ln2bf = qbuf;                    // 42.5 MiB (31..73.5); disjoint from dbuf
  u16* hbuf  = (u16*)(ws + 74 * MiB);   // 85 MiB (74..159); disjoint from ln2bf

  // merged weight conversion fp32 -> bf16 (dsts contiguous at ws+7MiB)
  k_wconv<<<3145728 / 256, 256, 0, stream>>>(wqkv, wout, wfc1, wfc2, wqb);

  k_langmean<<<BB, 256, 0, stream>>>(lang, lm);
  k_score<<<NPATCH * BB, 256, 0, stream>>>(x, lm, score);
  k_select<<<BB, 1024, 0, stream>>>(score, wall, rowmap, selsrc, lowlist);
  k_lowtok<<<dim3(BB, 4), 256, 0, stream>>>(x, wall, lowlist, lowtok);
  k_lnseq<<<dim3(SP, BB), 256, 0, stream>>>(x, lowtok, selsrc, ln1w, ln1b, lnseq);

  {
    Epi e = {};
    e.bias = bqkv; e.qb = qbuf; e.kb = kbuf; e.vtb = vtb; e.mvalid = M1P;
    k_gemm6<0><<<dim3(M1P / 128, 3072 / 256), 256, 0, stream>>>(lnseq, 1024, wqb, 1024, 1024, e);
  }

  k_attn2<<<BB * 16 * NQC, 256, 0, stream>>>(qbuf, kbuf, vtb, aout);

  {
    Epi e = {};
    e.bias = bout; e.obf = dbuf; e.mvalid = M1P; e.ldc = 1024;
    k_gemm5<1><<<dim3(M1P / 128, 1024 / 128), 256, 0, stream>>>(aout, 1024, wob, 1024, 1024, e);
  }

  k_scatln<<<M2P, 256, 0, stream>>>(x, dbuf, rowmap, ln2w, ln2b, out, ln2bf);

  // MLP: M-split into two row-halves; per half, fc1 over full hidden (N=4096,
  // ldc=4096 into hbuf) then fc2 as a single K=4096 pass -> ONE fp32 RMW of out.
  for (int mc = 0; mc < 2; mc++) {
    int rvalid = (mc == 0) ? MHALF : (M2 - MHALF);   // 10880, 10784
    Epi e2 = {};
    e2.bias = bfc1; e2.obf = hbuf; e2.mvalid = MHALF; e2.ldc = 4096;
    k_gemm6<2><<<dim3(MHALF / 128, 4096 / 256), 256, 0, stream>>>(
        ln2bf + (long)mc * MHALF * 1024, 1024, wf1b, 1024, 1024, e2);
    Epi e3 = {};
    e3.bias = bfc2; e3.of = out + (long)mc * MHALF * CC; e3.mvalid = rvalid;
    k_gemm5<3><<<dim3(MHALF / 128, 1024 / 128), 256, 0, stream>>>(
        hbuf, 4096, wf2b, 4096, 4096, e3);
  }
}

// Round 14
// 1002.111 us; speedup vs baseline: 1.0999x; 1.0114x over previous
//
#include <hip/hip_runtime.h>
#include <hip/hip_bf16.h>

typedef unsigned short u16;
typedef __attribute__((ext_vector_type(4))) float f32x4;
typedef __attribute__((ext_vector_type(8))) short s16x8;

#define DEVI __device__ __forceinline__

static constexpr int NPATCH = 676;
static constexpr int KSEL   = 540;   // int(676*0.8)
static constexpr int NLOW   = 136;
static constexpr int BB     = 32;
static constexpr int CC     = 1024;
static constexpr int S      = 542;   // 1 + 540 + 1
static constexpr int SP     = 576;   // padded seq (9*64)
static constexpr int M1P    = SP * BB;     // 18432 rows, seq-major: m = b*SP + s
static constexpr int NTOK   = 677;
static constexpr int M2     = NTOK * BB;   // 21664
static constexpr int M2P    = 21760;       // pad to 128/256
static constexpr int MHALF  = 10880;       // M2P/2 (85*128)
static constexpr int NKT    = SP / 64;     // 9 kv tiles
static constexpr int NQC    = 5;           // q-chunks of 8 qtiles (36 qtiles total)

DEVI u16 f2bf(float f) {
  unsigned u = __float_as_uint(f);
  u += 0x7fffu + ((u >> 16) & 1u);
  return (u16)(u >> 16);
}
// HW RTNE cast (compiler pairs into v_cvt_pk_bf16_f32); bit-identical to f2bf
DEVI u16 f2bf_fast(float f) {
  __hip_bfloat16 h = __float2bfloat16(f);
  return *(u16*)&h;
}
DEVI float bf2f(u16 h) { return __uint_as_float(((unsigned)h) << 16); }
DEVI float ex2(float x) { float r; asm("v_exp_f32 %0, %1" : "=v"(r) : "v"(x)); return r; }

DEVI void gld16(const void* g, void* l) {
  __builtin_amdgcn_global_load_lds((const __attribute__((address_space(1))) void*)g,
                                   (__attribute__((address_space(3))) void*)l,
                                   16, 0, 0);
}

DEVI void BAR() {
  asm volatile("" ::: "memory");
  __builtin_amdgcn_s_barrier();
  asm volatile("" ::: "memory");
}
#define VMC(N) asm volatile("s_waitcnt vmcnt(" #N ")" ::: "memory")

// ---------------- small kernels ----------------

// merged weight conversion: 4 fp32 sources -> contiguous bf16 region
__global__ void k_wconv(const float* __restrict__ s0, const float* __restrict__ s1,
                        const float* __restrict__ s2, const float* __restrict__ s3,
                        u16* __restrict__ out) {
  int i = blockIdx.x * blockDim.x + threadIdx.x;   // float4 index, total 3145728
  const float* src;
  long off;
  if (i < 786432)       { src = s0; off = 0; }
  else if (i < 1048576) { src = s1; off = 786432; }
  else if (i < 2097152) { src = s2; off = 1048576; }
  else                  { src = s3; off = 2097152; }
  float4 v = ((const float4*)src)[i - off];
  unsigned long long p = (unsigned long long)f2bf(v.x)
                       | ((unsigned long long)f2bf(v.y) << 16)
                       | ((unsigned long long)f2bf(v.z) << 32)
                       | ((unsigned long long)f2bf(v.w) << 48);
  *(unsigned long long*)&out[(long)i * 4] = p;
}

__global__ void k_langmean(const float* __restrict__ lang, float* __restrict__ lm) {
  int b = blockIdx.x, t = threadIdx.x;
  float a0 = 0, a1 = 0, a2 = 0, a3 = 0;
  for (int l = 0; l < 77; l++) {
    float4 v = ((const float4*)(lang + ((long)l * BB + b) * CC))[t];
    a0 += v.x; a1 += v.y; a2 += v.z; a3 += v.w;
  }
  const float inv = 1.f / 77.f;
  float4 o; o.x = a0 * inv; o.y = a1 * inv; o.z = a2 * inv; o.w = a3 * inv;
  ((float4*)(lm + b * CC))[t] = o;
}

__global__ void k_score(const float* __restrict__ x, const float* __restrict__ lm,
                        float* __restrict__ score) {
  int nb = blockIdx.x;
  int n = nb >> 5, b = nb & 31;
  int t = threadIdx.x;
  float4 xv = ((const float4*)(x + ((long)(n + 1) * BB + b) * CC))[t];
  float4 lv = ((const float4*)(lm + b * CC))[t];
  float s = xv.x * lv.x + xv.y * lv.y + xv.z * lv.z + xv.w * lv.w;
  for (int m = 1; m < 64; m <<= 1) s += __shfl_xor(s, m);
  __shared__ float sm[4];
  if ((t & 63) == 0) sm[t >> 6] = s;
  __syncthreads();
  if (t == 0) score[n * BB + b] = sm[0] + sm[1] + sm[2] + sm[3];
}

__global__ void k_select(const float* __restrict__ score, float* __restrict__ wall,
                         int* __restrict__ rowmap, int* __restrict__ selsrc,
                         int* __restrict__ lowlist) {
  int b = blockIdx.x, t = threadIdx.x;
  __shared__ float sc[NPATCH];
  __shared__ int hf[NPATCH];
  __shared__ float red[2];
  if (t < NPATCH) sc[t] = score[t * BB + b];
  __syncthreads();
  int high = 0;
  if (t < NPATCH) {
    float s = sc[t];
    int r = 0;
    for (int m = 0; m < NPATCH; m++) {
      float sm_ = sc[m];
      r += (sm_ > s) || (sm_ == s && m < t);
    }
    high = (r < KSEL);
    hf[t] = high;
  }
  __syncthreads();
  if (t < NPATCH) {
    int p = 0;
    for (int m = 0; m < t; m++) p += hf[m];
    if (high) {
      rowmap[b * NPATCH + t] = 1 + p;
      selsrc[b * S + 1 + p] = t + 1;        // row index into full x
    } else {
      rowmap[b * NPATCH + t] = S - 1;
      lowlist[b * NLOW + (t - p)] = t;
    }
  }
  if (t == 0) selsrc[b * S + 0] = 0;
  __syncthreads();
  if (t == 0) {
    float m = -3e38f;
    for (int i = 0; i < NPATCH; i++) if (!hf[i]) m = fmaxf(m, sc[i]);
    float d = 0;
    for (int i = 0; i < NPATCH; i++) if (!hf[i]) d += __expf(sc[i] - m);
    red[0] = m; red[1] = d;
  }
  __syncthreads();
  if (t < NPATCH) wall[b * NPATCH + t] = hf[t] ? 0.f : __expf(sc[t] - red[0]) / red[1];
}

__global__ void k_lowtok(const float* __restrict__ x, const float* __restrict__ wall,
                         const int* __restrict__ lowlist, float* __restrict__ lowtok) {
  int b = blockIdx.x, ch = blockIdx.y;
  int c = ch * 256 + threadIdx.x;
  float acc = 0.f;
  for (int i = 0; i < NLOW; i++) {
    int n = lowlist[b * NLOW + i];
    acc += wall[b * NPATCH + n] * x[((long)(n + 1) * BB + b) * CC + c];
  }
  lowtok[b * CC + c] = acc;
}

// gather + LayerNorm -> bf16 seq rows, SEQ-MAJOR: row = b*SP + s (pad rows zeroed)
__global__ void k_lnseq(const float* __restrict__ x, const float* __restrict__ lowtok,
                        const int* __restrict__ selsrc, const float* __restrict__ w,
                        const float* __restrict__ bias, u16* __restrict__ out) {
  int s = blockIdx.x, b = blockIdx.y, t = threadIdx.x;
  u16* orow = out + ((long)b * SP + s) * CC;
  if (s >= S) { *(unsigned long long*)&orow[4 * t] = 0ULL; return; }
  const float* src;
  if (s == 0)          src = x + (long)b * CC;
  else if (s == S - 1) src = lowtok + (long)b * CC;
  else                 src = x + ((long)selsrc[b * S + s] * BB + b) * CC;
  float4 v = ((const float4*)src)[t];
  float ss = v.x + v.y + v.z + v.w;
  float s2 = v.x * v.x + v.y * v.y + v.z * v.z + v.w * v.w;
  for (int k = 1; k < 64; k <<= 1) { ss += __shfl_xor(ss, k); s2 += __shfl_xor(s2, k); }
  __shared__ float sa[4], sb[4];
  if ((t & 63) == 0) { sa[t >> 6] = ss; sb[t >> 6] = s2; }
  __syncthreads();
  ss = sa[0] + sa[1] + sa[2] + sa[3];
  s2 = sb[0] + sb[1] + sb[2] + sb[3];
  float mu = ss * (1.f / CC);
  float var = s2 * (1.f / CC) - mu * mu;
  float rs = rsqrtf(var + 1e-5f);
  int c = 4 * t;
  unsigned long long p = (unsigned long long)f2bf((v.x - mu) * rs * w[c]     + bias[c])
                       | ((unsigned long long)f2bf((v.y - mu) * rs * w[c + 1] + bias[c + 1]) << 16)
                       | ((unsigned long long)f2bf((v.z - mu) * rs * w[c + 2] + bias[c + 2]) << 32)
                       | ((unsigned long long)f2bf((v.w - mu) * rs * w[c + 3] + bias[c + 3]) << 48);
  *(unsigned long long*)&orow[4 * t] = p;
}

// fused scatter (x + gathered d -> out fp32) + LayerNorm(out) -> bf16
__global__ void k_scatln(const float* __restrict__ x, const u16* __restrict__ dbuf,
                         const int* __restrict__ rowmap, const float* __restrict__ w,
                         const float* __restrict__ bias, float* __restrict__ out,
                         u16* __restrict__ lnout) {
  int m = blockIdx.x, t = threadIdx.x;
  u16* orow = lnout + (long)m * CC;
  if (m >= M2) { *(unsigned long long*)&orow[4 * t] = 0ULL; return; }
  int nf = m >> 5, b = m & 31;
  int srow = (nf == 0) ? 0 : rowmap[b * NPATCH + (nf - 1)];
  float4 xv = ((const float4*)(x + (long)m * CC))[t];
  unsigned long long dp = *(const unsigned long long*)&dbuf[((long)b * SP + srow) * CC + 4 * t];
  float4 v;
  v.x = xv.x + bf2f((u16)(dp));
  v.y = xv.y + bf2f((u16)(dp >> 16));
  v.z = xv.z + bf2f((u16)(dp >> 32));
  v.w = xv.w + bf2f((u16)(dp >> 48));
  ((float4*)(out + (long)m * CC))[t] = v;
  float ss = v.x + v.y + v.z + v.w;
  float s2 = v.x * v.x + v.y * v.y + v.z * v.z + v.w * v.w;
  for (int k = 1; k < 64; k <<= 1) { ss += __shfl_xor(ss, k); s2 += __shfl_xor(s2, k); }
  __shared__ float sa[4], sb[4];
  if ((t & 63) == 0) { sa[t >> 6] = ss; sb[t >> 6] = s2; }
  __syncthreads();
  ss = sa[0] + sa[1] + sa[2] + sa[3];
  s2 = sb[0] + sb[1] + sb[2] + sb[3];
  float mu = ss * (1.f / CC);
  float var = s2 * (1.f / CC) - mu * mu;
  float rs = rsqrtf(var + 1e-5f);
  int c = 4 * t;
  unsigned long long p = (unsigned long long)f2bf((v.x - mu) * rs * w[c]     + bias[c])
                       | ((unsigned long long)f2bf((v.y - mu) * rs * w[c + 1] + bias[c + 1]) << 16)
                       | ((unsigned long long)f2bf((v.z - mu) * rs * w[c + 2] + bias[c + 2]) << 32)
                       | ((unsigned long long)f2bf((v.w - mu) * rs * w[c + 3] + bias[c + 3]) << 48);
  *(unsigned long long*)&orow[4 * t] = p;
}

// ---------------- GEMM common ----------------

struct Epi {
  const float* bias;
  u16* obf;
  float* of;
  u16 *qb, *kb, *vtb;
  int mvalid, ldc;
};

// 128x32 K-step tile packed as 64 LDS-rows x 64 cols (8 KiB).
DEVI void stage32(u16* dst, const u16* src, int ld) {
  int t = threadIdx.x;
#pragma unroll
  for (int q = 0; q < 2; q++) {
    int s = t + q * 256;
    int R = s >> 3, clp = s & 7;
    int lc = clp ^ (R & 7);
    int m = 2 * R + (lc >> 2), kc = lc & 3;
    gld16(src + (long)m * ld + kc * 8, dst + s * 8);
  }
}

DEVI s16x8 frag32(const u16* tile, int m, int h4) {
  int R = m >> 1;
  int phys = ((((m & 1) << 2) | h4) ^ (R & 7));
  return *(const s16x8*)(tile + R * 64 + phys * 8);
}

// attn helpers (64-row x 64-col tiles, verified swizzle pair)
DEVI void stage64(u16* dst, const u16* src, int ld) {
  int t = threadIdx.x;
  int c = t & 7, r0 = t >> 3;             // rows 0..31
  gld16(src + (long)r0 * ld + ((c ^ (r0 & 7)) << 3), dst + t * 8);
  int r1 = r0 + 32;
  gld16(src + (long)r1 * ld + ((c ^ (r1 & 7)) << 3), dst + 2048 + t * 8);
}

DEVI s16x8 frag(const u16* half, int rh, int kk, int h4) {
  int chunk = ((kk << 2) | h4) ^ (rh & 7);
  return *(const s16x8*)(half + rh * 64 + chunk * 8);
}

// shared epilogue element-writer
template<int MODE>
DEVI void epi_store(const Epi& e, int m0, int n, const f32x4& a, float bias) {
  const float QSC = 0.125f * 1.44269504088896f;
  if (MODE == 0) {
    int part = n >> 10, cc = n & 1023;
    int hh = cc >> 6, dd = cc & 63;
    int b0 = m0 / SP, s0 = m0 % SP;
    if (part == 2) {
      u16 pk[4];
#pragma unroll
      for (int tt = 0; tt < 4; tt++) pk[tt] = f2bf(a[tt] + bias);
      *(unsigned long long*)&e.vtb[((long)(b0 * 16 + hh) * 64 + dd) * SP + s0] =
          *(unsigned long long*)pk;
    } else {
      u16* dst = (part == 0 ? e.qb : e.kb) + ((long)(b0 * 16 + hh) * SP + s0) * 64 + dd;
      float scl = (part == 0) ? QSC : 1.f;
#pragma unroll
      for (int tt = 0; tt < 4; tt++) dst[tt * 64] = f2bf((a[tt] + bias) * scl);
    }
  } else if (MODE == 1) {
#pragma unroll
    for (int tt = 0; tt < 4; tt++)
      e.obf[(long)(m0 + tt) * e.ldc + n] = f2bf(a[tt] + bias);
  } else if (MODE == 2) {
#pragma unroll
    for (int tt = 0; tt < 4; tt++) {
      float v = a[tt] + bias;
      v = v / (1.f + __expf(-1.702f * v));
      e.obf[(long)(m0 + tt) * e.ldc + n] = f2bf(v);
    }
  } else {
#pragma unroll
    for (int tt = 0; tt < 4; tt++) {
      int m = m0 + tt;
      if (m < e.mvalid) e.of[(long)m * CC + n] += a[tt] + bias;
    }
  }
}

// -- GEMM v5: 128x128 tile, BK=32, 3-buffer rotation, counted vmcnt (outproj/fc2) --

template<int MODE>
__global__ __launch_bounds__(256, 3) void k_gemm5(const u16* __restrict__ A, int lda,
                                                  const u16* __restrict__ Bw, int ldb,
                                                  int K, Epi e) {
  __shared__ __align__(16) u16 lds[3][2][4096];  // 48 KiB -> 3 blk/CU
  int t = threadIdx.x;
  int lane = t & 63, w = t >> 6;
  int h4 = lane >> 4, r = lane & 15;
  int wr = w >> 1, wc = w & 1;
  int MBk = gridDim.x, NBk = gridDim.y;
  int nwg = MBk * NBk;
  int orig = blockIdx.y * MBk + blockIdx.x;
  int q8 = nwg >> 3, r8 = nwg & 7, xcd = orig & 7, rk = orig >> 3;
  int wgid = (xcd < r8 ? xcd * (q8 + 1) : r8 * (q8 + 1) + (xcd - r8) * q8) + rk;
  int bm = wgid / NBk, bn = wgid % NBk;

  const u16* Asrc = A + (long)bm * 128 * lda;
  const u16* Bsrc = Bw + (long)bn * 128 * ldb;
  int NT = K >> 5;

  f32x4 acc[4][4];
#pragma unroll
  for (int i = 0; i < 4; i++)
#pragma unroll
    for (int j = 0; j < 4; j++) acc[i][j] = {0.f, 0.f, 0.f, 0.f};

  stage32(lds[0][0], Asrc, lda);
  stage32(lds[0][1], Bsrc, ldb);
  if (NT > 1) {
    stage32(lds[1][0], Asrc + 32, lda);
    stage32(lds[1][1], Bsrc + 32, ldb);
  }

  int bufr = 0, bufw = 2;
  for (int kt = 0; kt < NT; kt++) {
    if (kt + 1 < NT) { VMC(4); } else { VMC(0); }
    BAR();
    if (kt + 2 < NT) {
      stage32(lds[bufw][0], Asrc + (kt + 2) * 32, lda);
      stage32(lds[bufw][1], Bsrc + (kt + 2) * 32, ldb);
    }
    const u16* At = lds[bufr][0];
    const u16* Bt = lds[bufr][1];
    s16x8 af[4], bf[4];
#pragma unroll
    for (int i = 0; i < 4; i++) af[i] = frag32(At, wr * 64 + i * 16 + r, h4);
#pragma unroll
    for (int j = 0; j < 4; j++) bf[j] = frag32(Bt, wc * 64 + j * 16 + r, h4);
#pragma unroll
    for (int i = 0; i < 4; i++)
#pragma unroll
      for (int j = 0; j < 4; j++)
        acc[i][j] = __builtin_amdgcn_mfma_f32_16x16x32_bf16(af[i], bf[j], acc[i][j], 0, 0, 0);
    bufr = (bufr == 2) ? 0 : bufr + 1;
    bufw = (bufw == 2) ? 0 : bufw + 1;
  }

#pragma unroll
  for (int i = 0; i < 4; i++) {
    int m0 = bm * 128 + wr * 64 + i * 16 + 4 * h4;
#pragma unroll
    for (int j = 0; j < 4; j++) {
      int n = bn * 128 + wc * 64 + j * 16 + r;
      float bias = (MODE == 3 && e.bias == nullptr) ? 0.f : e.bias[n];
      epi_store<MODE>(e, m0, n, acc[i][j], bias);
    }
  }
}

// -- GEMM v7: 128x256 tile, BK=32, 3-buffer rotation, counted vmcnt (QKV/fc1) --
// Replaces gemm6's sync pipeline: the per-iter __syncthreads drained vmcnt(0),
// serializing a full global-load latency every K-step at only 2 blk/CU.

template<int MODE>
__global__ __launch_bounds__(256, 2) void k_gemm7(const u16* __restrict__ A, int lda,
                                                  const u16* __restrict__ Bw, int ldb,
                                                  int K, Epi e) {
  __shared__ __align__(16) u16 lds[3][3][4096];  // [buf][A,B-lo,B-hi] = 72 KiB -> 2 blk/CU
  int t = threadIdx.x;
  int lane = t & 63, w = t >> 6;
  int h4 = lane >> 4, r = lane & 15;
  int wr = w >> 1, wc = w & 1;          // per-wave 64 rows x 128 cols
  int MBk = gridDim.x, NBk = gridDim.y;
  int nwg = MBk * NBk;
  int orig = blockIdx.y * MBk + blockIdx.x;
  int q8 = nwg >> 3, r8 = nwg & 7, xcd = orig & 7, rk = orig >> 3;
  int wgid = (xcd < r8 ? xcd * (q8 + 1) : r8 * (q8 + 1) + (xcd - r8) * q8) + rk;
  int bm = wgid / NBk, bn = wgid % NBk;

  const u16* Asrc = A + (long)bm * 128 * lda;
  const u16* Bsrc = Bw + (long)bn * 256 * ldb;
  int NT = K >> 5;

  f32x4 acc[4][8];
#pragma unroll
  for (int i = 0; i < 4; i++)
#pragma unroll
    for (int j = 0; j < 8; j++) acc[i][j] = {0.f, 0.f, 0.f, 0.f};

  // prologue: stage tiles 0 and 1 (6 loads/thread each)
  stage32(lds[0][0], Asrc, lda);
  stage32(lds[0][1], Bsrc, ldb);
  stage32(lds[0][2], Bsrc + (long)128 * ldb, ldb);
  if (NT > 1) {
    stage32(lds[1][0], Asrc + 32, lda);
    stage32(lds[1][1], Bsrc + 32, ldb);
    stage32(lds[1][2], Bsrc + (long)128 * ldb + 32, ldb);
  }

  int bufr = 0, bufw = 2;
  for (int kt = 0; kt < NT; kt++) {
    // tile kt's 6 loads complete (kt+1's 6 may remain in flight)
    if (kt + 1 < NT) { VMC(6); } else { VMC(0); }
    BAR();   // publishes tile-kt staging; orders stage(kt+2) after all waves'
             // tile-(kt-1) reads (those precede this barrier in program order)
    if (kt + 2 < NT) {
      stage32(lds[bufw][0], Asrc + (kt + 2) * 32, lda);
      stage32(lds[bufw][1], Bsrc + (kt + 2) * 32, ldb);
      stage32(lds[bufw][2], Bsrc + (long)128 * ldb + (kt + 2) * 32, ldb);
    }
    const u16* At = lds[bufr][0];
    const u16* Bt = lds[bufr][1 + wc];   // wc=0 -> n 0..127, wc=1 -> n 128..255
    s16x8 af[4], bf[8];
#pragma unroll
    for (int i = 0; i < 4; i++) af[i] = frag32(At, wr * 64 + i * 16 + r, h4);
#pragma unroll
    for (int j = 0; j < 8; j++) bf[j] = frag32(Bt, j * 16 + r, h4);
#pragma unroll
    for (int i = 0; i < 4; i++)
#pragma unroll
      for (int j = 0; j < 8; j++)
        acc[i][j] = __builtin_amdgcn_mfma_f32_16x16x32_bf16(af[i], bf[j], acc[i][j], 0, 0, 0);
    bufr = (bufr == 2) ? 0 : bufr + 1;
    bufw = (bufw == 2) ? 0 : bufw + 1;
  }

#pragma unroll
  for (int i = 0; i < 4; i++) {
    int m0 = bm * 128 + wr * 64 + i * 16 + 4 * h4;
#pragma unroll
    for (int j = 0; j < 8; j++) {
      int n = bn * 256 + wc * 128 + j * 16 + r;
      float bias = (MODE == 3 && e.bias == nullptr) ? 0.f : e.bias[n];
      epi_store<MODE>(e, m0, n, acc[i][j], bias);
    }
  }
}

// ---- flash attention v3: LDS-staged KV, MFMA row-sums (ones-trick), cheap defer-max ----

__global__ __launch_bounds__(256, 4) void k_attn2(const u16* __restrict__ qb,
                                                  const u16* __restrict__ kb,
                                                  const u16* __restrict__ vtb,
                                                  u16* __restrict__ aout) {
  __shared__ __align__(16) u16 Kt[2][4096];
  __shared__ __align__(16) u16 Vt[2][4096];
  __shared__ __align__(16) u16 Pl[4][1024];

  int nwg = gridDim.x;                   // 2560
  int orig = blockIdx.x;
  int q8 = nwg >> 3, r8 = nwg & 7, xcd = orig & 7, rk = orig >> 3;
  int wgid = (xcd < r8 ? xcd * (q8 + 1) : r8 * (q8 + 1) + (xcd - r8) * q8) + rk;
  int bh = wgid / NQC, qc = wgid % NQC;  // all q-chunks of a (b,h) contiguous -> same XCD
  int b = bh >> 4, hh = bh & 15;
  int t = threadIdx.x, w = t >> 6, lane = t & 63;
  int h4 = lane >> 4, r = lane & 15;

  const u16* Q  = qb  + (long)bh * SP * 64;
  const u16* Kg = kb  + (long)bh * SP * 64;
  const u16* Vg = vtb + (long)bh * 64 * SP;

  s16x8 ones;
#pragma unroll
  for (int j = 0; j < 8; j++) ones[j] = (short)0x3F80;   // bf16 1.0

  int qt[2];
  bool act[2];
  s16x8 aq0[2], aq1[2];
  f32x4 o[2][4];
  f32x4 ls[2];                            // P row-sums, accumulated by MFMA ones-trick
  float mM[2][4];
#pragma unroll
  for (int sub = 0; sub < 2; sub++) {
    qt[sub] = qc * 8 + w * 2 + sub;
    act[sub] = qt[sub] < SP / 16;
    if (act[sub]) {
      aq0[sub] = *(const s16x8*)&Q[(qt[sub] * 16 + r) * 64 + h4 * 8];
      aq1[sub] = *(const s16x8*)&Q[(qt[sub] * 16 + r) * 64 + 32 + h4 * 8];
    }
    ls[sub] = {0.f, 0.f, 0.f, 0.f};
#pragma unroll
    for (int i = 0; i < 4; i++) { o[sub][i] = {0.f, 0.f, 0.f, 0.f}; mM[sub][i] = -1e30f; }
  }

  // prologue: stage tile 0
  stage64(Kt[0], Kg, 64);
  stage64(Vt[0], Vg, SP);
  VMC(0);
  BAR();

  for (int kt = 0; kt < NKT; kt++) {
    int cur = kt & 1;
    if (kt + 1 < NKT) {                 // issue next-tile loads (other buffer)
      stage64(Kt[cur ^ 1], Kg + (kt + 1) * 64 * 64, 64);
      stage64(Vt[cur ^ 1], Vg + (kt + 1) * 64, SP);
    }
    int kv0 = kt * 64;
    const u16* Kc = Kt[cur];
    const u16* Vc = Vt[cur];
#pragma unroll
    for (int sub = 0; sub < 2; sub++) {
      if (!act[sub]) continue;
      // ---- QK^T: S[q16][kv64]
      f32x4 sf[4];
#pragma unroll
      for (int f = 0; f < 4; f++) {
        sf[f] = {0.f, 0.f, 0.f, 0.f};
        sf[f] = __builtin_amdgcn_mfma_f32_16x16x32_bf16(aq0[sub], frag(Kc, f * 16 + r, 0, h4), sf[f], 0, 0, 0);
        sf[f] = __builtin_amdgcn_mfma_f32_16x16x32_bf16(aq1[sub], frag(Kc, f * 16 + r, 1, h4), sf[f], 0, 0, 0);
      }
      if (kv0 + 64 > S) {               // mask invalid kv columns
#pragma unroll
        for (int f = 0; f < 4; f++)
          if (kv0 + f * 16 + r >= S) {
#pragma unroll
            for (int tt = 0; tt < 4; tt++) sf[f][tt] = -1e30f;
          }
      }
      // ---- defer-max: cheap lane-local test; full reduce only when exceeded
      float mxl[4];
#pragma unroll
      for (int tt = 0; tt < 4; tt++)
        mxl[tt] = fmaxf(fmaxf(sf[0][tt], sf[1][tt]), fmaxf(sf[2][tt], sf[3][tt]));
      int need = 0;
#pragma unroll
      for (int tt = 0; tt < 4; tt++) need |= (mxl[tt] > mM[sub][tt] + 8.f);
      if (__any(need)) {                // rare after first tile
        for (int msk = 1; msk < 16; msk <<= 1) {
#pragma unroll
          for (int tt = 0; tt < 4; tt++) mxl[tt] = fmaxf(mxl[tt], __shfl_xor(mxl[tt], msk));
        }
#pragma unroll
        for (int tt = 0; tt < 4; tt++) {
          float mn = fmaxf(mM[sub][tt], mxl[tt]);
          float sc = ex2(mM[sub][tt] - mn);
          mM[sub][tt] = mn;
          ls[sub][tt] *= sc;
#pragma unroll
          for (int nf = 0; nf < 4; nf++) o[sub][nf][tt] *= sc;
        }
      }
      // ---- P = 2^(s - m)
#pragma unroll
      for (int tt = 0; tt < 4; tt++) {
        float m_ = mM[sub][tt];
        sf[0][tt] = ex2(sf[0][tt] - m_);
        sf[1][tt] = ex2(sf[1][tt] - m_);
        sf[2][tt] = ex2(sf[2][tt] - m_);
        sf[3][tt] = ex2(sf[3][tt] - m_);
      }
      // ---- pack P -> LDS (HW RTNE cvt, compiler pairs to v_cvt_pk_bf16_f32)
      u16* Pw = Pl[w];
#pragma unroll
      for (int f = 0; f < 4; f++)
#pragma unroll
        for (int tt = 0; tt < 4; tt++) {
          int q = 4 * h4 + tt;
          int chunk = (f * 2 + (r >> 3)) ^ (q & 7);
          Pw[q * 64 + chunk * 8 + (r & 7)] = f2bf_fast(sf[f][tt]);
        }
      // ---- PV + row-sum (B = ones: every output column holds sum_k P[q][k])
      s16x8 pa0 = frag(Pw, r, 0, h4);
      s16x8 pa1 = frag(Pw, r, 1, h4);
#pragma unroll
      for (int nf = 0; nf < 4; nf++) {
        o[sub][nf] = __builtin_amdgcn_mfma_f32_16x16x32_bf16(pa0, frag(Vc, nf * 16 + r, 0, h4), o[sub][nf], 0, 0, 0);
        o[sub][nf] = __builtin_amdgcn_mfma_f32_16x16x32_bf16(pa1, frag(Vc, nf * 16 + r, 1, h4), o[sub][nf], 0, 0, 0);
      }
      ls[sub] = __builtin_amdgcn_mfma_f32_16x16x32_bf16(pa0, ones, ls[sub], 0, 0, 0);
      ls[sub] = __builtin_amdgcn_mfma_f32_16x16x32_bf16(pa1, ones, ls[sub], 0, 0, 0);
    }
    VMC(0);
    BAR();
  }

  // ---- write output
#pragma unroll
  for (int sub = 0; sub < 2; sub++) {
    if (!act[sub]) continue;
    float inv[4];
#pragma unroll
    for (int tt = 0; tt < 4; tt++) inv[tt] = 1.f / ls[sub][tt];
#pragma unroll
    for (int nf = 0; nf < 4; nf++)
#pragma unroll
      for (int tt = 0; tt < 4; tt++) {
        int q = qt[sub] * 16 + 4 * h4 + tt;
        if (q < S) aout[((long)b * SP + q) * CC + hh * 64 + nf * 16 + r] = f2bf_fast(o[sub][nf][tt] * inv[tt]);
      }
  }
}

// ---------------- launcher ----------------
// ws liveness map (MiB):
//   0..7      small scratch
//   7..31     weights (contiguous bf16): wqb 7..13, wob 13..15, wf1b 15..23, wf2b 23..31
//   31..67    qbuf   (QKV gemm -> attn)
//   67..103   kbuf   (QKV gemm -> attn)
//  103..139   vtb    (QKV gemm -> attn); THEN dbuf (outproj -> scatln)
//  139..175   regA:  lnseq (lnseq -> QKV gemm); then aout (attn -> outproj)
//   31..73.5  ln2bf  (scatln -> fc1)  [over dead qbuf+kbuf-head; disjoint from dbuf]
//   74..159   hbuf   (fc1 chunk -> fc2 chunk) [MHALF x 4096 bf16 = 85 MiB]
// peak 175 MiB.

extern "C" void kernel_launch(void* const* d_in, const int* in_sizes, int n_in,
                              void* d_out, int out_size, void* d_ws, size_t ws_size,
                              hipStream_t stream) {
  const float* x    = (const float*)d_in[0];
  const float* lang = (const float*)d_in[1];
  const float* ln1w = (const float*)d_in[2];
  const float* ln1b = (const float*)d_in[3];
  const float* ln2w = (const float*)d_in[4];
  const float* ln2b = (const float*)d_in[5];
  const float* wqkv = (const float*)d_in[6];
  const float* bqkv = (const float*)d_in[7];
  const float* wout = (const float*)d_in[8];
  const float* bout = (const float*)d_in[9];
  const float* wfc1 = (const float*)d_in[10];
  const float* bfc1 = (const float*)d_in[11];
  const float* wfc2 = (const float*)d_in[12];
  const float* bfc2 = (const float*)d_in[13];
  float* out = (float*)d_out;
  char* ws = (char*)d_ws;
  const size_t MiB = 1ull << 20;

  float* lm      = (float*)(ws + 0 * MiB);
  float* score   = (float*)(ws + 1 * MiB);
  float* wall    = (float*)(ws + 2 * MiB);
  int*   rowmap  = (int*)  (ws + 3 * MiB);
  int*   selsrc  = (int*)  (ws + 4 * MiB);
  int*   lowlist = (int*)  (ws + 5 * MiB);
  float* lowtok  = (float*)(ws + 6 * MiB);
  u16* wqb  = (u16*)(ws + 7 * MiB);
  u16* wob  = (u16*)(ws + 13 * MiB);
  u16* wf1b = (u16*)(ws + 15 * MiB);
  u16* wf2b = (u16*)(ws + 23 * MiB);
  u16* qbuf = (u16*)(ws + 31 * MiB);
  u16* kbuf = (u16*)(ws + 67 * MiB);
  u16* vtb  = (u16*)(ws + 103 * MiB);
  u16* regA = (u16*)(ws + 139 * MiB);   // lnseq -> aout (36 MiB each, M1P rows)
  u16* lnseq = regA;
  u16* aout  = regA;
  u16* dbuf  = vtb;                     // outproj output; vtb dead after attn
  u16* ln2bf = qbuf;                    // 42.5 MiB (31..73.5); disjoint from dbuf
  u16* hbuf  = (u16*)(ws + 74 * MiB);   // 85 MiB (74..159); disjoint from ln2bf

  // merged weight conversion fp32 -> bf16 (dsts contiguous at ws+7MiB)
  k_wconv<<<3145728 / 256, 256, 0, stream>>>(wqkv, wout, wfc1, wfc2, wqb);

  k_langmean<<<BB, 256, 0, stream>>>(lang, lm);
  k_score<<<NPATCH * BB, 256, 0, stream>>>(x, lm, score);
  k_select<<<BB, 1024, 0, stream>>>(score, wall, rowmap, selsrc, lowlist);
  k_lowtok<<<dim3(BB, 4), 256, 0, stream>>>(x, wall, lowlist, lowtok);
  k_lnseq<<<dim3(SP, BB), 256, 0, stream>>>(x, lowtok, selsrc, ln1w, ln1b, lnseq);

  {
    Epi e = {};
    e.bias = bqkv; e.qb = qbuf; e.kb = kbuf; e.vtb = vtb; e.mvalid = M1P;
    k_gemm7<0><<<dim3(M1P / 128, 3072 / 256), 256, 0, stream>>>(lnseq, 1024, wqb, 1024, 1024, e);
  }

  k_attn2<<<BB * 16 * NQC, 256, 0, stream>>>(qbuf, kbuf, vtb, aout);

  {
    Epi e = {};
    e.bias = bout; e.obf = dbuf; e.mvalid = M1P; e.ldc = 1024;
    k_gemm5<1><<<dim3(M1P / 128, 1024 / 128), 256, 0, stream>>>(aout, 1024, wob, 1024, 1024, e);
  }

  k_scatln<<<M2P, 256, 0, stream>>>(x, dbuf, rowmap, ln2w, ln2b, out, ln2bf);

  // MLP: M-split into two row-halves; per half, fc1 over full hidden (N=4096,
  // ldc=4096 into hbuf) then fc2 as a single K=4096 pass -> ONE fp32 RMW of out.
  for (int mc = 0; mc < 2; mc++) {
    int rvalid = (mc == 0) ? MHALF : (M2 - MHALF);   // 10880, 10784
    Epi e2 = {};
    e2.bias = bfc1; e2.obf = hbuf; e2.mvalid = MHALF; e2.ldc = 4096;
    k_gemm7<2><<<dim3(MHALF / 128, 4096 / 256), 256, 0, stream>>>(
        ln2bf + (long)mc * MHALF * 1024, 1024, wf1b, 1024, 1024, e2);
    Epi e3 = {};
    e3.bias = bfc2; e3.of = out + (long)mc * MHALF * CC; e3.mvalid = rvalid;
    k_gemm5<3><<<dim3(MHALF / 128, 1024 / 128), 256, 0, stream>>>(
        hbuf, 4096, wf2b, 4096, 4096, e3);
  }
}